// Round 5
// baseline (187.633 us; speedup 1.0000x reference)
//
#include <hip/hip_runtime.h>
#include <math.h>

#define DM 256
#define SQ 4096
#define BT 2
#define NS 16
#define NTOK (BT*SQ)
#define NCHK 64
#define CHL (SQ/NCHK)

typedef __attribute__((ext_vector_type(8))) short short8;
typedef __attribute__((ext_vector_type(4))) float f32x4;

__device__ __forceinline__ float sigm_(float x){ return 1.f/(1.f+__expf(-x)); }
__device__ __forceinline__ float silu_(float x){ return x*sigm_(x); }
__device__ __forceinline__ float softplus_(float x){ return (x>20.f)? x : log1pf(__expf(x)); }
__device__ __forceinline__ unsigned short f2bf(float f){
  unsigned int u = __float_as_uint(f);
  unsigned int r = (u + 0x7FFFu + ((u>>16)&1u)) >> 16;
  return (unsigned short)r;
}
__device__ __forceinline__ float bf2f(unsigned short u){
  return __uint_as_float(((unsigned int)u)<<16);
}

// ---------- fused LN stats + apply + bf16 convert: one wave per token ----------
__global__ __launch_bounds__(256) void k_lncvt(const float* __restrict__ x,
                                               const float* __restrict__ g, const float* __restrict__ nb,
                                               unsigned short* __restrict__ xl){
  int tok = blockIdx.x*4 + (threadIdx.x>>6);
  int lane = threadIdx.x & 63;
  const float* row = x + (size_t)tok*DM;
  float4 v = *(const float4*)(row + lane*4);
  float s = v.x+v.y+v.z+v.w;
  float ss = v.x*v.x+v.y*v.y+v.z*v.z+v.w*v.w;
  #pragma unroll
  for (int o=32;o>0;o>>=1){ s += __shfl_xor(s,o,64); ss += __shfl_xor(ss,o,64); }
  float m = s*(1.f/DM);
  float r = rsqrtf(ss*(1.f/DM)-m*m+1e-5f);
  float4 gv = *(const float4*)(g + lane*4);
  float4 bv = *(const float4*)(nb + lane*4);
  ushort4 o4;
  o4.x = f2bf((v.x-m)*r*gv.x+bv.x);
  o4.y = f2bf((v.y-m)*r*gv.y+bv.y);
  o4.z = f2bf((v.z-m)*r*gv.z+bv.z);
  o4.w = f2bf((v.w-m)*r*gv.w+bv.w);
  *(ushort4*)(xl + (size_t)tok*DM + lane*4) = o4;
}

// ---------- generic fp32 -> bf16 (size = grid*1024 elements) ----------
__global__ __launch_bounds__(256) void k_wcvt(const float* __restrict__ W, unsigned short* __restrict__ Wb){
  int i = (blockIdx.x*256 + threadIdx.x)*4;
  float4 v = *(const float4*)(W + i);
  ushort4 o4; o4.x=f2bf(v.x); o4.y=f2bf(v.y); o4.z=f2bf(v.z); o4.w=f2bf(v.w);
  *(ushort4*)(Wb + i) = o4;
}

// ---------- in_proj via MFMA: C[8192][512] = xl @ Wb^T, split into xin|z ----------
__global__ __launch_bounds__(256) void k_inproj_mfma(
    const unsigned short* __restrict__ xl, const unsigned short* __restrict__ Wb,
    float* __restrict__ xin, float* __restrict__ z)
{
  int tid = threadIdx.x;
  int wid = tid >> 6, lane = tid & 63;
  int wm = wid >> 1, wn = wid & 1;
  int row0 = blockIdx.x*128 + wm*64;
  int col0 = blockIdx.y*64 + wn*32;
  int lr = lane & 15;
  int lg = lane >> 4;
  f32x4 acc[4][2];
  #pragma unroll
  for (int m=0;m<4;m++)
    #pragma unroll
    for (int n=0;n<2;n++) acc[m][n] = (f32x4){0.f,0.f,0.f,0.f};

  #pragma unroll
  for (int k0=0;k0<DM;k0+=32){
    short8 a[4], b[2];
    #pragma unroll
    for (int m=0;m<4;m++)
      a[m] = *(const short8*)(xl + (size_t)(row0 + m*16 + lr)*DM + k0 + lg*8);
    #pragma unroll
    for (int n=0;n<2;n++)
      b[n] = *(const short8*)(Wb + (size_t)(col0 + n*16 + lr)*DM + k0 + lg*8);
    #pragma unroll
    for (int m=0;m<4;m++)
      #pragma unroll
      for (int n=0;n<2;n++)
        acc[m][n] = __builtin_amdgcn_mfma_f32_16x16x32_bf16(a[m], b[n], acc[m][n], 0,0,0);
  }
  float* outp; int cb;
  if (blockIdx.y < 4){ outp = xin; cb = col0; } else { outp = z; cb = col0 - 256; }
  #pragma unroll
  for (int m=0;m<4;m++)
    #pragma unroll
    for (int n=0;n<2;n++)
      #pragma unroll
      for (int r=0;r<4;r++){
        int rr = row0 + m*16 + lg*4 + r;
        int cc = cb + n*16 + lr;
        outp[(size_t)rr*DM + cc] = acc[m][n][r];
      }
}

// ---------- causal depthwise conv (K=4) + silu, fp32 + bf16 outputs ----------
__global__ __launch_bounds__(256) void k_conv(
    const float* __restrict__ xin,
    const float* __restrict__ cw_f, const float* __restrict__ cb_f,
    const float* __restrict__ cw_b, const float* __restrict__ cb_b,
    float* __restrict__ uf, float* __restrict__ ub,
    unsigned short* __restrict__ ufb, unsigned short* __restrict__ ubb)
{
  int d = threadIdx.x;
  int b = blockIdx.y;
  int dir = blockIdx.z;
  int t0 = blockIdx.x*16;
  const float* w  = dir? cw_b : cw_f;
  const float* bi = dir? cb_b : cb_f;
  float w0=w[d*4], w1=w[d*4+1], w2=w[d*4+2], w3=w[d*4+3];
  float bb = bi[d];
  float* out = dir? ub : uf;
  unsigned short* outb = dir? ubb : ufb;
  const float* xbase = xin + (size_t)b*SQ*DM + d;
  float xm3 = (t0-3>=0)? xbase[(size_t)(dir?(SQ-1-(t0-3)):(t0-3))*DM] : 0.f;
  float xm2 = (t0-2>=0)? xbase[(size_t)(dir?(SQ-1-(t0-2)):(t0-2))*DM] : 0.f;
  float xm1 = (t0-1>=0)? xbase[(size_t)(dir?(SQ-1-(t0-1)):(t0-1))*DM] : 0.f;
  for (int i=0;i<16;i++){
    int t = t0+i;
    float xt = xbase[(size_t)(dir?(SQ-1-t):t)*DM];
    float v = silu_(bb + w0*xm3 + w1*xm2 + w2*xm1 + w3*xt);
    size_t idx = ((size_t)b*SQ+t)*DM + d;
    out[idx] = v;
    outb[idx] = f2bf(v);
    xm3=xm2; xm2=xm1; xm1=xt;
  }
}

// ---------- build Wcat[dir][320][256] bf16: rows 0..255 = W2 = dtw@xw[:16];
//            rows 256..287 = xw[16..47]; rows 288..319 = 0 ----------
__global__ __launch_bounds__(256) void k_wcat(
    const float* __restrict__ xw_f, const float* __restrict__ xw_b,
    const float* __restrict__ dtw_f, const float* __restrict__ dtw_b,
    unsigned short* __restrict__ Wcatb)
{
  int kc = blockIdx.x*64;
  int dir = blockIdx.y;
  const float* xw  = dir? xw_b : xw_f;
  const float* dtw = dir? dtw_b : dtw_f;
  int d = threadIdx.x;
  float dw[16];
  #pragma unroll
  for (int r=0;r<16;r++) dw[r] = dtw[d*16+r];
  unsigned short* Wd = Wcatb + (size_t)dir*320*DM + (size_t)d*DM + kc;
  for (int kk=0;kk<64;kk++){
    float acc = 0.f;
    #pragma unroll
    for (int r=0;r<16;r++) acc += dw[r]*xw[r*DM + kc + kk];
    Wd[kk] = f2bf(acc);
  }
  if (d < 64){
    unsigned short* Wr = Wcatb + (size_t)dir*320*DM + (size_t)(256+d)*DM + kc;
    if (d < 32){
      const float* src = xw + (size_t)(16+d)*DM + kc;
      for (int kk=0;kk<64;kk++) Wr[kk] = f2bf(src[kk]);
    } else {
      for (int kk=0;kk<64;kk++) Wr[kk] = 0;
    }
  }
}

// ---------- xproj+dtproj via MFMA: [8192][320] = u_bf16 @ Wcat^T ----------
// y<4: dt = softplus(. + bias) -> bf16 ; y==4: cols 0..15 -> Bm, 16..31 -> Cm
__global__ __launch_bounds__(256) void k_xproj_mfma(
    const unsigned short* __restrict__ ufb, const unsigned short* __restrict__ ubb,
    const unsigned short* __restrict__ Wcatb,
    const float* __restrict__ dtbias_f, const float* __restrict__ dtbias_b,
    unsigned short* __restrict__ dt16f, unsigned short* __restrict__ dt16b,
    float* __restrict__ bmf, float* __restrict__ cmf,
    float* __restrict__ bmb, float* __restrict__ cmb)
{
  int dir = blockIdx.z;
  const unsigned short* u  = dir? ubb : ufb;
  const unsigned short* Wc = Wcatb + (size_t)dir*320*DM;
  const float* dbi = dir? dtbias_b : dtbias_f;
  unsigned short* dt = dir? dt16b : dt16f;
  float* bm = dir? bmb : bmf;
  float* cm = dir? cmb : cmf;
  int tid = threadIdx.x;
  int wid = tid >> 6, lane = tid & 63;
  int wm = wid >> 1, wn = wid & 1;
  int row0 = blockIdx.x*128 + wm*64;
  int col0 = blockIdx.y*64 + wn*32;
  int lr = lane & 15, lg = lane >> 4;
  f32x4 acc[4][2];
  #pragma unroll
  for (int m=0;m<4;m++)
    #pragma unroll
    for (int n=0;n<2;n++) acc[m][n] = (f32x4){0.f,0.f,0.f,0.f};
  #pragma unroll
  for (int k0=0;k0<DM;k0+=32){
    short8 a[4], b[2];
    #pragma unroll
    for (int m=0;m<4;m++)
      a[m] = *(const short8*)(u + (size_t)(row0 + m*16 + lr)*DM + k0 + lg*8);
    #pragma unroll
    for (int n=0;n<2;n++)
      b[n] = *(const short8*)(Wc + (size_t)(col0 + n*16 + lr)*DM + k0 + lg*8);
    #pragma unroll
    for (int m=0;m<4;m++)
      #pragma unroll
      for (int n=0;n<2;n++)
        acc[m][n] = __builtin_amdgcn_mfma_f32_16x16x32_bf16(a[m], b[n], acc[m][n], 0,0,0);
  }
  if (blockIdx.y < 4){
    #pragma unroll
    for (int n=0;n<2;n++){
      int cc = col0 + n*16 + lr;
      float bias = dbi[cc];
      #pragma unroll
      for (int m=0;m<4;m++)
        #pragma unroll
        for (int r=0;r<4;r++){
          int rr = row0 + m*16 + lg*4 + r;
          dt[(size_t)rr*DM + cc] = f2bf(softplus_(acc[m][n][r] + bias));
        }
    }
  } else if (wn == 0){
    #pragma unroll
    for (int n=0;n<2;n++){
      float* outp = n ? cm : bm;
      #pragma unroll
      for (int m=0;m<4;m++)
        #pragma unroll
        for (int r=0;r<4;r++){
          int rr = row0 + m*16 + lg*4 + r;
          outp[(size_t)rr*NS + lr] = acc[m][n][r];
        }
    }
  }
}

// ---------- scan phase 1: per-chunk summaries (Aprod, h_end) ----------
__global__ __launch_bounds__(256) void k_scan1(
    const unsigned short* __restrict__ dtf, const unsigned short* __restrict__ dtb,
    const float* __restrict__ uf, const float* __restrict__ ub,
    const float* __restrict__ bmf, const float* __restrict__ bmb,
    const float* __restrict__ alog_f, const float* __restrict__ alog_b,
    float* __restrict__ apf, float* __restrict__ hsf,
    float* __restrict__ apb, float* __restrict__ hsb)
{
  int c = blockIdx.x, b = blockIdx.y, dir = blockIdx.z;
  const unsigned short* dt = dir? dtb : dtf;
  const float* u  = dir? ub  : uf;
  const float* bmp= dir? bmb : bmf;
  const float* al = dir? alog_b : alog_f;
  float* ap = dir? apb : apf;
  float* hs = dir? hsb : hsf;
  int d = threadIdx.x;
  __shared__ float sB[CHL*NS];
  for (int i=threadIdx.x;i<CHL*NS;i+=256) sB[i] = bmp[((size_t)b*SQ + c*CHL)*NS + i];
  float A[NS];
  #pragma unroll
  for (int n=0;n<NS;n++) A[n] = -__expf(al[d*NS+n]);
  float h[NS] = {};
  float dts = 0.f;
  __syncthreads();
  for (int t=0;t<CHL;t++){
    size_t idx = ((size_t)b*SQ + c*CHL + t)*DM + d;
    float dtv = bf2f(dt[idx]);
    float uv  = u[idx];
    float du  = dtv*uv;
    dts += dtv;
    #pragma unroll
    for (int n=0;n<NS;n++) h[n] = h[n]*__expf(dtv*A[n]) + du*sB[t*NS+n];
  }
  size_t o = (((size_t)b*NCHK + c)*DM + d)*NS;
  #pragma unroll
  for (int n=0;n<NS;n++){ hs[o+n] = h[n]; ap[o+n] = __expf(A[n]*dts); }
}

// ---------- scan phase 2: sequential scan over chunk summaries ----------
__global__ __launch_bounds__(256) void k_scan2(
    float* __restrict__ apf, float* __restrict__ hsf,
    float* __restrict__ apb, float* __restrict__ hsb)
{
  int gid = blockIdx.x*256 + threadIdx.x;
  int dir = gid >> 13;
  int rem = gid & 8191;
  int b   = rem >> 12;
  int dn  = rem & 4095;
  const float* ap = dir? apb : apf;
  float* hs = dir? hsb : hsf;
  float h = 0.f;
  for (int c=0;c<NCHK;c++){
    size_t idx = ((size_t)b*NCHK + c)*4096 + dn;
    float a = ap[idx];
    float v = hs[idx];
    hs[idx] = h;
    h = h*a + v;
  }
}

// ---------- scan phase 3: replay with prefix, emit y (both dirs) ----------
__global__ __launch_bounds__(256) void k_scan3(
    const unsigned short* __restrict__ dtf, const unsigned short* __restrict__ dtb,
    const float* __restrict__ uf, const float* __restrict__ ub,
    const float* __restrict__ bmf, const float* __restrict__ bmb,
    const float* __restrict__ cmf, const float* __restrict__ cmb,
    const float* __restrict__ alf, const float* __restrict__ alb,
    const float* __restrict__ Df, const float* __restrict__ Db,
    const float* __restrict__ z,
    const float* __restrict__ hsf, const float* __restrict__ hsb,
    float* __restrict__ yf, float* __restrict__ yb, int dir_base)
{
  int c = blockIdx.x, b = blockIdx.y;
  int dir = blockIdx.z + dir_base;
  const unsigned short* dt = dir? dtb : dtf;
  const float* u  = dir? ub  : uf;
  const float* bmp= dir? bmb : bmf;
  const float* cmp= dir? cmb : cmf;
  const float* al = dir? alb : alf;
  const float* Dv = dir? Db  : Df;
  const float* hs = dir? hsb : hsf;
  float* yout = dir? yb : yf;
  int d = threadIdx.x;
  __shared__ float sB[CHL*NS];
  __shared__ float sC[CHL*NS];
  for (int i=threadIdx.x;i<CHL*NS;i+=256){
    sB[i] = bmp[((size_t)b*SQ + c*CHL)*NS + i];
    sC[i] = cmp[((size_t)b*SQ + c*CHL)*NS + i];
  }
  float A[NS], h[NS];
  size_t o = (((size_t)b*NCHK + c)*DM + d)*NS;
  #pragma unroll
  for (int n=0;n<NS;n++){ A[n] = -__expf(al[d*NS+n]); h[n] = hs[o+n]; }
  float Dd = Dv[d];
  __syncthreads();
  for (int t=0;t<CHL;t++){
    int gt = c*CHL + t;
    size_t idx = ((size_t)b*SQ + gt)*DM + d;
    float dtv = bf2f(dt[idx]);
    float uv  = u[idx];
    float du  = dtv*uv;
    float y = 0.f;
    #pragma unroll
    for (int n=0;n<NS;n++){
      h[n] = h[n]*__expf(dtv*A[n]) + du*sB[t*NS+n];
      y += h[n]*sC[t*NS+n];
    }
    y += uv*Dd;
    int torig = dir ? (SQ-1-gt) : gt;
    size_t oidx = ((size_t)b*SQ + torig)*DM + d;
    float zv = z[oidx];
    yout[oidx] = y * (zv * sigm_(zv));
  }
}

// ---------- y-combine + out-LN + bf16 convert: one wave per token ----------
__global__ __launch_bounds__(256) void k_ycvt(const float* __restrict__ yf, const float* __restrict__ yb,
                                              const float* __restrict__ og, const float* __restrict__ ob,
                                              unsigned short* __restrict__ ybf){
  int tok = blockIdx.x*4 + (threadIdx.x>>6);
  int lane = threadIdx.x & 63;
  size_t base = (size_t)tok*DM;
  float4 vf = *(const float4*)(yf + base + lane*4);
  float4 vb = *(const float4*)(yb + base + lane*4);
  float4 v; v.x=0.5f*(vf.x+vb.x); v.y=0.5f*(vf.y+vb.y); v.z=0.5f*(vf.z+vb.z); v.w=0.5f*(vf.w+vb.w);
  float s = v.x+v.y+v.z+v.w;
  float ss = v.x*v.x+v.y*v.y+v.z*v.z+v.w*v.w;
  #pragma unroll
  for (int o=32;o>0;o>>=1){ s += __shfl_xor(s,o,64); ss += __shfl_xor(ss,o,64); }
  float m = s*(1.f/DM);
  float r = rsqrtf(ss*(1.f/DM)-m*m+1e-5f);
  float4 gv = *(const float4*)(og + lane*4);
  float4 bv = *(const float4*)(ob + lane*4);
  ushort4 o4;
  o4.x = f2bf((v.x-m)*r*gv.x+bv.x);
  o4.y = f2bf((v.y-m)*r*gv.y+bv.y);
  o4.z = f2bf((v.z-m)*r*gv.z+bv.z);
  o4.w = f2bf((v.w-m)*r*gv.w+bv.w);
  *(ushort4*)(ybf + base + lane*4) = o4;
}

// ---------- final via MFMA: C[8192][256] = ybf @ Woutb^T, post-LN + skip ----------
#define SOS 266
__global__ __launch_bounds__(256) void k_final_mfma(
    const unsigned short* __restrict__ ybf, const unsigned short* __restrict__ Wb,
    const float* __restrict__ pg, const float* __restrict__ pb,
    const float* __restrict__ skip, float* __restrict__ out)
{
  __shared__ float sOut[32*SOS];
  __shared__ float sm[32], sr[32];
  int tid = threadIdx.x;
  int wid = tid >> 6, lane = tid & 63;
  int lr = lane & 15, lg = lane >> 4;
  int row0 = blockIdx.x*32;
  int col0 = wid*64;
  f32x4 acc[2][4];
  #pragma unroll
  for (int m=0;m<2;m++)
    #pragma unroll
    for (int n=0;n<4;n++) acc[m][n] = (f32x4){0.f,0.f,0.f,0.f};
  #pragma unroll
  for (int k0=0;k0<DM;k0+=32){
    short8 a[2], b[4];
    #pragma unroll
    for (int m=0;m<2;m++)
      a[m] = *(const short8*)(ybf + (size_t)(row0 + m*16 + lr)*DM + k0 + lg*8);
    #pragma unroll
    for (int n=0;n<4;n++)
      b[n] = *(const short8*)(Wb + (size_t)(col0 + n*16 + lr)*DM + k0 + lg*8);
    #pragma unroll
    for (int m=0;m<2;m++)
      #pragma unroll
      for (int n=0;n<4;n++)
        acc[m][n] = __builtin_amdgcn_mfma_f32_16x16x32_bf16(a[m], b[n], acc[m][n], 0,0,0);
  }
  #pragma unroll
  for (int m=0;m<2;m++)
    #pragma unroll
    for (int n=0;n<4;n++)
      #pragma unroll
      for (int r=0;r<4;r++)
        sOut[(m*16 + lg*4 + r)*SOS + col0 + n*16 + lr] = acc[m][n][r];
  __syncthreads();
  for (int j=0;j<8;j++){
    int rrow = wid*8 + j;
    const float* rp = &sOut[rrow*SOS + lane*4];
    float2 v0 = *(const float2*)(rp);
    float2 v1 = *(const float2*)(rp+2);
    float s = v0.x+v0.y+v1.x+v1.y;
    float ss = v0.x*v0.x+v0.y*v0.y+v1.x*v1.x+v1.y*v1.y;
    #pragma unroll
    for (int o=32;o>0;o>>=1){ s += __shfl_xor(s,o,64); ss += __shfl_xor(ss,o,64); }
    if (lane==0){ float m=s*(1.f/DM); sm[rrow]=m; sr[rrow]=rsqrtf(ss*(1.f/DM)-m*m+1e-5f); }
  }
  __syncthreads();
  float gv = pg[tid], bv = pb[tid];
  for (int rrow=0;rrow<32;rrow++){
    int tok = row0 + rrow;
    float v = (sOut[rrow*SOS + tid]-sm[rrow])*sr[rrow]*gv + bv + skip[(size_t)tok*DM + tid];
    out[(size_t)tok*DM + tid] = v;
  }
}

extern "C" void kernel_launch(void* const* d_in, const int* in_sizes, int n_in,
                              void* d_out, int out_size, void* d_ws, size_t ws_size,
                              hipStream_t stream)
{
  const float* input      = (const float*)d_in[0];
  const float* norm_g     = (const float*)d_in[1];
  const float* norm_b     = (const float*)d_in[2];
  const float* in_proj_w  = (const float*)d_in[3];
  const float* conv_w     = (const float*)d_in[4];
  const float* conv_b     = (const float*)d_in[5];
  const float* xproj_w    = (const float*)d_in[6];
  const float* dtproj_w   = (const float*)d_in[7];
  const float* dtproj_b   = (const float*)d_in[8];
  const float* A_log      = (const float*)d_in[9];
  const float* Dp         = (const float*)d_in[10];
  const float* conv_w_b   = (const float*)d_in[11];
  const float* conv_b_b   = (const float*)d_in[12];
  const float* xproj_w_b  = (const float*)d_in[13];
  const float* dtproj_w_b = (const float*)d_in[14];
  const float* dtproj_b_b = (const float*)d_in[15];
  const float* A_log_b    = (const float*)d_in[16];
  const float* Dp_b       = (const float*)d_in[17];
  const float* out_norm_g = (const float*)d_in[18];
  const float* out_norm_b = (const float*)d_in[19];
  const float* out_proj_w = (const float*)d_in[20];
  const float* post_norm_g= (const float*)d_in[21];
  const float* post_norm_b= (const float*)d_in[22];
  float* out = (float*)d_out;

  float* ws = (float*)d_ws;
  const size_t M2 = (size_t)NTOK*DM;           // 2,097,152 floats (8 MB)
  const size_t SCH = (size_t)BT*NCHK*DM*NS;    // 524,288 floats (2 MB)
  float* xin = ws;                 // reused as y_f
  float* z   = ws + M2;
  float* uf  = ws + 2*M2;
  float* ub  = ws + 3*M2;
  // slot 4: dt bf16 (fwd 4MB + bwd 4MB)
  unsigned short* dt16f = (unsigned short*)(ws + 4*M2);
  unsigned short* dt16b = dt16f + M2;
  // slot 5: u bf16 (fwd 4MB + bwd 4MB)
  unsigned short* ufb = (unsigned short*)(ws + 5*M2);
  unsigned short* ubb = ufb + M2;
  float* p   = ws + 6*M2;
  float* bmf = p;              p += (size_t)NTOK*NS;
  float* cmf = p;              p += (size_t)NTOK*NS;
  float* bmb = p;              p += (size_t)NTOK*NS;
  float* cmb = p;              p += (size_t)NTOK*NS;
  float* apf = p;              p += SCH;
  float* hsf = p;              p += SCH;
  float* apb = p;              p += SCH;
  float* hsb = p;              p += SCH;
  size_t base_floats = (size_t)(p - ws);
  // bf16 staging aliases (all dead before the scan kernels write ap/hs):
  unsigned short* xlbf  = (unsigned short*)apf;  // 4 MB spans apf+hsf (dead after inproj)
  unsigned short* Wbf   = (unsigned short*)apb;  // 256 KB (dead after inproj)
  unsigned short* Wcatb = (unsigned short*)apf;  // 320 KB (written after inproj, dead after xproj)
  unsigned short* ybf   = (unsigned short*)apf;  // 4 MB (after scan3, scan ws dead)
  unsigned short* Woutb = (unsigned short*)apb;  // 128 KB (after scan2)
  bool big = ws_size >= (base_floats + M2 + 1024)*sizeof(float);
  float* yf = xin;
  float* yb = big ? (ws + base_floats) : uf;

  k_lncvt<<<NTOK/4, 256, 0, stream>>>(input, norm_g, norm_b, xlbf);
  k_wcvt<<<(2*DM*DM)/1024, 256, 0, stream>>>(in_proj_w, Wbf);
  k_inproj_mfma<<<dim3(NTOK/128, 8, 1), 256, 0, stream>>>(xlbf, Wbf, xin, z);
  k_conv<<<dim3(SQ/16, BT, 2), 256, 0, stream>>>(xin, conv_w, conv_b, conv_w_b, conv_b_b,
                                                 uf, ub, ufb, ubb);
  k_wcat<<<dim3(4, 2), 256, 0, stream>>>(xproj_w, xproj_w_b, dtproj_w, dtproj_w_b, Wcatb);
  k_xproj_mfma<<<dim3(NTOK/128, 5, 2), 256, 0, stream>>>(ufb, ubb, Wcatb,
                                                         dtproj_b, dtproj_b_b,
                                                         dt16f, dt16b, bmf, cmf, bmb, cmb);
  k_scan1<<<dim3(NCHK, BT, 2), 256, 0, stream>>>(dt16f, dt16b, uf, ub, bmf, bmb, A_log, A_log_b,
                                                 apf, hsf, apb, hsb);
  k_scan2<<<64, 256, 0, stream>>>(apf, hsf, apb, hsb);
  k_wcvt<<<(DM*DM)/1024, 256, 0, stream>>>(out_proj_w, Woutb);
  if (big){
    k_scan3<<<dim3(NCHK, BT, 2), 256, 0, stream>>>(dt16f, dt16b, uf, ub, bmf, bmb, cmf, cmb,
                                                   A_log, A_log_b, Dp, Dp_b, z, hsf, hsb,
                                                   yf, yb, 0);
  } else {
    k_scan3<<<dim3(NCHK, BT, 1), 256, 0, stream>>>(dt16f, dt16b, uf, ub, bmf, bmb, cmf, cmb,
                                                   A_log, A_log_b, Dp, Dp_b, z, hsf, hsb,
                                                   yf, yb, 0);
    k_scan3<<<dim3(NCHK, BT, 1), 256, 0, stream>>>(dt16f, dt16b, uf, ub, bmf, bmb, cmf, cmb,
                                                   A_log, A_log_b, Dp, Dp_b, z, hsf, hsb,
                                                   yf, yb, 1);
  }
  k_ycvt<<<NTOK/4, 256, 0, stream>>>(yf, yb, out_norm_g, out_norm_b, ybf);
  k_final_mfma<<<NTOK/32, 256, 0, stream>>>(ybf, Woutb, post_norm_g, post_norm_b, input, out);
}

// Round 6
// 160.658 us; speedup vs baseline: 1.1679x; 1.1679x over previous
//
#include <hip/hip_runtime.h>
#include <math.h>

#define DM 256
#define SQ 4096
#define BT 2
#define NS 16
#define NTOK (BT*SQ)
#define NCHK 128
#define CHL (SQ/NCHK)

typedef __attribute__((ext_vector_type(8))) short short8;
typedef __attribute__((ext_vector_type(4))) float f32x4;

__device__ __forceinline__ float sigm_(float x){ return 1.f/(1.f+__expf(-x)); }
__device__ __forceinline__ float silu_(float x){ return x*sigm_(x); }
__device__ __forceinline__ float softplus_(float x){ return (x>20.f)? x : log1pf(__expf(x)); }
__device__ __forceinline__ unsigned short f2bf(float f){
  unsigned int u = __float_as_uint(f);
  unsigned int r = (u + 0x7FFFu + ((u>>16)&1u)) >> 16;
  return (unsigned short)r;
}
__device__ __forceinline__ float bf2f(unsigned short u){
  return __uint_as_float(((unsigned int)u)<<16);
}

// ---------- fused LN stats + apply + bf16 convert: one wave per token ----------
__global__ __launch_bounds__(256) void k_lncvt(const float* __restrict__ x,
                                               const float* __restrict__ g, const float* __restrict__ nb,
                                               unsigned short* __restrict__ xl){
  int tok = blockIdx.x*4 + (threadIdx.x>>6);
  int lane = threadIdx.x & 63;
  const float* row = x + (size_t)tok*DM;
  float4 v = *(const float4*)(row + lane*4);
  float s = v.x+v.y+v.z+v.w;
  float ss = v.x*v.x+v.y*v.y+v.z*v.z+v.w*v.w;
  #pragma unroll
  for (int o=32;o>0;o>>=1){ s += __shfl_xor(s,o,64); ss += __shfl_xor(ss,o,64); }
  float m = s*(1.f/DM);
  float r = rsqrtf(ss*(1.f/DM)-m*m+1e-5f);
  float4 gv = *(const float4*)(g + lane*4);
  float4 bv = *(const float4*)(nb + lane*4);
  ushort4 o4;
  o4.x = f2bf((v.x-m)*r*gv.x+bv.x);
  o4.y = f2bf((v.y-m)*r*gv.y+bv.y);
  o4.z = f2bf((v.z-m)*r*gv.z+bv.z);
  o4.w = f2bf((v.w-m)*r*gv.w+bv.w);
  *(ushort4*)(xl + (size_t)tok*DM + lane*4) = o4;
}

// ---------- generic fp32 -> bf16 (size = grid*1024 elements) ----------
__global__ __launch_bounds__(256) void k_wcvt(const float* __restrict__ W, unsigned short* __restrict__ Wb){
  int i = (blockIdx.x*256 + threadIdx.x)*4;
  float4 v = *(const float4*)(W + i);
  ushort4 o4; o4.x=f2bf(v.x); o4.y=f2bf(v.y); o4.z=f2bf(v.z); o4.w=f2bf(v.w);
  *(ushort4*)(Wb + i) = o4;
}

// ---------- in_proj via MFMA: [8192][512] = xl @ Wb^T -> xin fp32 | z bf16 ----------
__global__ __launch_bounds__(256) void k_inproj_mfma(
    const unsigned short* __restrict__ xl, const unsigned short* __restrict__ Wb,
    float* __restrict__ xin, unsigned short* __restrict__ zb)
{
  int tid = threadIdx.x;
  int wid = tid >> 6, lane = tid & 63;
  int wm = wid >> 1, wn = wid & 1;
  int row0 = blockIdx.x*128 + wm*64;
  int col0 = blockIdx.y*64 + wn*32;
  int lr = lane & 15;
  int lg = lane >> 4;
  f32x4 acc[4][2];
  #pragma unroll
  for (int m=0;m<4;m++)
    #pragma unroll
    for (int n=0;n<2;n++) acc[m][n] = (f32x4){0.f,0.f,0.f,0.f};

  #pragma unroll
  for (int k0=0;k0<DM;k0+=32){
    short8 a[4], b[2];
    #pragma unroll
    for (int m=0;m<4;m++)
      a[m] = *(const short8*)(xl + (size_t)(row0 + m*16 + lr)*DM + k0 + lg*8);
    #pragma unroll
    for (int n=0;n<2;n++)
      b[n] = *(const short8*)(Wb + (size_t)(col0 + n*16 + lr)*DM + k0 + lg*8);
    #pragma unroll
    for (int m=0;m<4;m++)
      #pragma unroll
      for (int n=0;n<2;n++)
        acc[m][n] = __builtin_amdgcn_mfma_f32_16x16x32_bf16(a[m], b[n], acc[m][n], 0,0,0);
  }
  if (blockIdx.y < 4){
    #pragma unroll
    for (int m=0;m<4;m++)
      #pragma unroll
      for (int n=0;n<2;n++)
        #pragma unroll
        for (int r=0;r<4;r++){
          int rr = row0 + m*16 + lg*4 + r;
          int cc = col0 + n*16 + lr;
          xin[(size_t)rr*DM + cc] = acc[m][n][r];
        }
  } else {
    int cb = col0 - 256;
    #pragma unroll
    for (int m=0;m<4;m++)
      #pragma unroll
      for (int n=0;n<2;n++)
        #pragma unroll
        for (int r=0;r<4;r++){
          int rr = row0 + m*16 + lg*4 + r;
          int cc = cb + n*16 + lr;
          zb[(size_t)rr*DM + cc] = f2bf(acc[m][n][r]);
        }
  }
}

// ---------- causal depthwise conv (K=4) + silu -> u bf16 ----------
__global__ __launch_bounds__(256) void k_conv(
    const float* __restrict__ xin,
    const float* __restrict__ cw_f, const float* __restrict__ cb_f,
    const float* __restrict__ cw_b, const float* __restrict__ cb_b,
    unsigned short* __restrict__ ufb, unsigned short* __restrict__ ubb)
{
  int d = threadIdx.x;
  int b = blockIdx.y;
  int dir = blockIdx.z;
  int t0 = blockIdx.x*16;
  const float* w  = dir? cw_b : cw_f;
  const float* bi = dir? cb_b : cb_f;
  float w0=w[d*4], w1=w[d*4+1], w2=w[d*4+2], w3=w[d*4+3];
  float bb = bi[d];
  unsigned short* outb = dir? ubb : ufb;
  const float* xbase = xin + (size_t)b*SQ*DM + d;
  float xm3 = (t0-3>=0)? xbase[(size_t)(dir?(SQ-1-(t0-3)):(t0-3))*DM] : 0.f;
  float xm2 = (t0-2>=0)? xbase[(size_t)(dir?(SQ-1-(t0-2)):(t0-2))*DM] : 0.f;
  float xm1 = (t0-1>=0)? xbase[(size_t)(dir?(SQ-1-(t0-1)):(t0-1))*DM] : 0.f;
  for (int i=0;i<16;i++){
    int t = t0+i;
    float xt = xbase[(size_t)(dir?(SQ-1-t):t)*DM];
    float v = silu_(bb + w0*xm3 + w1*xm2 + w2*xm1 + w3*xt);
    outb[((size_t)b*SQ+t)*DM + d] = f2bf(v);
    xm3=xm2; xm2=xm1; xm1=xt;
  }
}

// ---------- build Wcat[dir][320][256] bf16: rows 0..255 = dtw@xw[:16];
//            rows 256..287 = xw[16..47]; rows 288..319 = 0 ----------
__global__ __launch_bounds__(256) void k_wcat(
    const float* __restrict__ xw_f, const float* __restrict__ xw_b,
    const float* __restrict__ dtw_f, const float* __restrict__ dtw_b,
    unsigned short* __restrict__ Wcatb)
{
  int kc = blockIdx.x*64;
  int dir = blockIdx.y;
  const float* xw  = dir? xw_b : xw_f;
  const float* dtw = dir? dtw_b : dtw_f;
  int d = threadIdx.x;
  float dw[16];
  #pragma unroll
  for (int r=0;r<16;r++) dw[r] = dtw[d*16+r];
  unsigned short* Wd = Wcatb + (size_t)dir*320*DM + (size_t)d*DM + kc;
  for (int kk=0;kk<64;kk++){
    float acc = 0.f;
    #pragma unroll
    for (int r=0;r<16;r++) acc += dw[r]*xw[r*DM + kc + kk];
    Wd[kk] = f2bf(acc);
  }
  if (d < 64){
    unsigned short* Wr = Wcatb + (size_t)dir*320*DM + (size_t)(256+d)*DM + kc;
    if (d < 32){
      const float* src = xw + (size_t)(16+d)*DM + kc;
      for (int kk=0;kk<64;kk++) Wr[kk] = f2bf(src[kk]);
    } else {
      for (int kk=0;kk<64;kk++) Wr[kk] = 0;
    }
  }
}

// ---------- xproj+dtproj via MFMA: [8192][320] = u_bf16 @ Wcat^T ----------
__global__ __launch_bounds__(256) void k_xproj_mfma(
    const unsigned short* __restrict__ ufb, const unsigned short* __restrict__ ubb,
    const unsigned short* __restrict__ Wcatb,
    const float* __restrict__ dtbias_f, const float* __restrict__ dtbias_b,
    unsigned short* __restrict__ dt16f, unsigned short* __restrict__ dt16b,
    float* __restrict__ bmf, float* __restrict__ cmf,
    float* __restrict__ bmb, float* __restrict__ cmb)
{
  int dir = blockIdx.z;
  const unsigned short* u  = dir? ubb : ufb;
  const unsigned short* Wc = Wcatb + (size_t)dir*320*DM;
  const float* dbi = dir? dtbias_b : dtbias_f;
  unsigned short* dt = dir? dt16b : dt16f;
  float* bm = dir? bmb : bmf;
  float* cm = dir? cmb : cmf;
  int tid = threadIdx.x;
  int wid = tid >> 6, lane = tid & 63;
  int wm = wid >> 1, wn = wid & 1;
  int row0 = blockIdx.x*128 + wm*64;
  int col0 = blockIdx.y*64 + wn*32;
  int lr = lane & 15, lg = lane >> 4;
  f32x4 acc[4][2];
  #pragma unroll
  for (int m=0;m<4;m++)
    #pragma unroll
    for (int n=0;n<2;n++) acc[m][n] = (f32x4){0.f,0.f,0.f,0.f};
  #pragma unroll
  for (int k0=0;k0<DM;k0+=32){
    short8 a[4], b[2];
    #pragma unroll
    for (int m=0;m<4;m++)
      a[m] = *(const short8*)(u + (size_t)(row0 + m*16 + lr)*DM + k0 + lg*8);
    #pragma unroll
    for (int n=0;n<2;n++)
      b[n] = *(const short8*)(Wc + (size_t)(col0 + n*16 + lr)*DM + k0 + lg*8);
    #pragma unroll
    for (int m=0;m<4;m++)
      #pragma unroll
      for (int n=0;n<2;n++)
        acc[m][n] = __builtin_amdgcn_mfma_f32_16x16x32_bf16(a[m], b[n], acc[m][n], 0,0,0);
  }
  if (blockIdx.y < 4){
    #pragma unroll
    for (int n=0;n<2;n++){
      int cc = col0 + n*16 + lr;
      float bias = dbi[cc];
      #pragma unroll
      for (int m=0;m<4;m++)
        #pragma unroll
        for (int r=0;r<4;r++){
          int rr = row0 + m*16 + lg*4 + r;
          dt[(size_t)rr*DM + cc] = f2bf(softplus_(acc[m][n][r] + bias));
        }
    }
  } else if (wn == 0){
    #pragma unroll
    for (int n=0;n<2;n++){
      float* outp = n ? cm : bm;
      #pragma unroll
      for (int m=0;m<4;m++)
        #pragma unroll
        for (int r=0;r<4;r++){
          int rr = row0 + m*16 + lg*4 + r;
          outp[(size_t)rr*NS + lr] = acc[m][n][r];
        }
    }
  }
}

// ---------- scan phase 1: per-chunk summaries (Aprod, h_end) ----------
__global__ __launch_bounds__(256) void k_scan1(
    const unsigned short* __restrict__ dtf, const unsigned short* __restrict__ dtb,
    const unsigned short* __restrict__ ufb, const unsigned short* __restrict__ ubb,
    const float* __restrict__ bmf, const float* __restrict__ bmb,
    const float* __restrict__ alog_f, const float* __restrict__ alog_b,
    float* __restrict__ apf, float* __restrict__ hsf,
    float* __restrict__ apb, float* __restrict__ hsb)
{
  int c = blockIdx.x, b = blockIdx.y, dir = blockIdx.z;
  const unsigned short* dt = dir? dtb : dtf;
  const unsigned short* u  = dir? ubb : ufb;
  const float* bmp= dir? bmb : bmf;
  const float* al = dir? alog_b : alog_f;
  float* ap = dir? apb : apf;
  float* hs = dir? hsb : hsf;
  int d = threadIdx.x;
  __shared__ float sB[CHL*NS];
  for (int i=threadIdx.x;i<CHL*NS;i+=256) sB[i] = bmp[((size_t)b*SQ + c*CHL)*NS + i];
  float A[NS];
  #pragma unroll
  for (int n=0;n<NS;n++) A[n] = -__expf(al[d*NS+n]);
  float h[NS] = {};
  float dts = 0.f;
  __syncthreads();
  for (int t=0;t<CHL;t++){
    size_t idx = ((size_t)b*SQ + c*CHL + t)*DM + d;
    float dtv = bf2f(dt[idx]);
    float uv  = bf2f(u[idx]);
    float du  = dtv*uv;
    dts += dtv;
    #pragma unroll
    for (int n=0;n<NS;n++) h[n] = h[n]*__expf(dtv*A[n]) + du*sB[t*NS+n];
  }
  size_t o = (((size_t)b*NCHK + c)*DM + d)*NS;
  #pragma unroll
  for (int n=0;n<NS;n++){ hs[o+n] = h[n]; ap[o+n] = __expf(A[n]*dts); }
}

// ---------- scan phase 2: sequential scan over chunk summaries ----------
__global__ __launch_bounds__(64) void k_scan2(
    float* __restrict__ apf, float* __restrict__ hsf,
    float* __restrict__ apb, float* __restrict__ hsb)
{
  int gid = blockIdx.x*64 + threadIdx.x;     // 0..16383
  int dir = gid >> 13;
  int rem = gid & 8191;
  int b   = rem >> 12;
  int dn  = rem & 4095;
  const float* ap = dir? apb : apf;
  float* hs = dir? hsb : hsf;
  size_t base = (size_t)b*NCHK*4096 + dn;
  float h = 0.f;
  for (int c=0;c<NCHK;c++){
    size_t idx = base + (size_t)c*4096;
    float a = ap[idx];
    float v = hs[idx];
    hs[idx] = h;
    h = h*a + v;
  }
}

// ---------- scan phase 3: replay with prefix, emit y (both dirs, one dispatch) ----------
__global__ __launch_bounds__(256) void k_scan3(
    const unsigned short* __restrict__ dtf, const unsigned short* __restrict__ dtb,
    const unsigned short* __restrict__ ufb, const unsigned short* __restrict__ ubb,
    const float* __restrict__ bmf, const float* __restrict__ bmb,
    const float* __restrict__ cmf, const float* __restrict__ cmb,
    const float* __restrict__ alf, const float* __restrict__ alb,
    const float* __restrict__ Df, const float* __restrict__ Db,
    const unsigned short* __restrict__ zb,
    const float* __restrict__ hsf, const float* __restrict__ hsb,
    float* __restrict__ yf, float* __restrict__ yb)
{
  int c = blockIdx.x, b = blockIdx.y;
  int dir = blockIdx.z;
  const unsigned short* dt = dir? dtb : dtf;
  const unsigned short* u  = dir? ubb : ufb;
  const float* bmp= dir? bmb : bmf;
  const float* cmp= dir? cmb : cmf;
  const float* al = dir? alb : alf;
  const float* Dv = dir? Db  : Df;
  const float* hs = dir? hsb : hsf;
  float* yout = dir? yb : yf;
  int d = threadIdx.x;
  __shared__ float sB[CHL*NS];
  __shared__ float sC[CHL*NS];
  for (int i=threadIdx.x;i<CHL*NS;i+=256){
    sB[i] = bmp[((size_t)b*SQ + c*CHL)*NS + i];
    sC[i] = cmp[((size_t)b*SQ + c*CHL)*NS + i];
  }
  float A[NS], h[NS];
  size_t o = (((size_t)b*NCHK + c)*DM + d)*NS;
  #pragma unroll
  for (int n=0;n<NS;n++){ A[n] = -__expf(al[d*NS+n]); h[n] = hs[o+n]; }
  float Dd = Dv[d];
  __syncthreads();
  for (int t=0;t<CHL;t++){
    int gt = c*CHL + t;
    size_t idx = ((size_t)b*SQ + gt)*DM + d;
    float dtv = bf2f(dt[idx]);
    float uv  = bf2f(u[idx]);
    float du  = dtv*uv;
    float y = 0.f;
    #pragma unroll
    for (int n=0;n<NS;n++){
      h[n] = h[n]*__expf(dtv*A[n]) + du*sB[t*NS+n];
      y += h[n]*sC[t*NS+n];
    }
    y += uv*Dd;
    int torig = dir ? (SQ-1-gt) : gt;
    size_t oidx = ((size_t)b*SQ + torig)*DM + d;
    float zv = bf2f(zb[oidx]);
    yout[oidx] = y * (zv * sigm_(zv));
  }
}

// ---------- y-combine + out-LN + bf16 convert: one wave per token ----------
__global__ __launch_bounds__(256) void k_ycvt(const float* __restrict__ yf, const float* __restrict__ yb,
                                              const float* __restrict__ og, const float* __restrict__ ob,
                                              unsigned short* __restrict__ ybf){
  int tok = blockIdx.x*4 + (threadIdx.x>>6);
  int lane = threadIdx.x & 63;
  size_t base = (size_t)tok*DM;
  float4 vf = *(const float4*)(yf + base + lane*4);
  float4 vb = *(const float4*)(yb + base + lane*4);
  float4 v; v.x=0.5f*(vf.x+vb.x); v.y=0.5f*(vf.y+vb.y); v.z=0.5f*(vf.z+vb.z); v.w=0.5f*(vf.w+vb.w);
  float s = v.x+v.y+v.z+v.w;
  float ss = v.x*v.x+v.y*v.y+v.z*v.z+v.w*v.w;
  #pragma unroll
  for (int o=32;o>0;o>>=1){ s += __shfl_xor(s,o,64); ss += __shfl_xor(ss,o,64); }
  float m = s*(1.f/DM);
  float r = rsqrtf(ss*(1.f/DM)-m*m+1e-5f);
  float4 gv = *(const float4*)(og + lane*4);
  float4 bv = *(const float4*)(ob + lane*4);
  ushort4 o4;
  o4.x = f2bf((v.x-m)*r*gv.x+bv.x);
  o4.y = f2bf((v.y-m)*r*gv.y+bv.y);
  o4.z = f2bf((v.z-m)*r*gv.z+bv.z);
  o4.w = f2bf((v.w-m)*r*gv.w+bv.w);
  *(ushort4*)(ybf + base + lane*4) = o4;
}

// ---------- final via MFMA: C[8192][256] = ybf @ Woutb^T, post-LN + skip ----------
#define SOS 266
__global__ __launch_bounds__(256) void k_final_mfma(
    const unsigned short* __restrict__ ybf, const unsigned short* __restrict__ Wb,
    const float* __restrict__ pg, const float* __restrict__ pb,
    const float* __restrict__ skip, float* __restrict__ out)
{
  __shared__ float sOut[32*SOS];
  __shared__ float sm[32], sr[32];
  int tid = threadIdx.x;
  int wid = tid >> 6, lane = tid & 63;
  int lr = lane & 15, lg = lane >> 4;
  int row0 = blockIdx.x*32;
  int col0 = wid*64;
  f32x4 acc[2][4];
  #pragma unroll
  for (int m=0;m<2;m++)
    #pragma unroll
    for (int n=0;n<4;n++) acc[m][n] = (f32x4){0.f,0.f,0.f,0.f};
  #pragma unroll
  for (int k0=0;k0<DM;k0+=32){
    short8 a[2], b[4];
    #pragma unroll
    for (int m=0;m<2;m++)
      a[m] = *(const short8*)(ybf + (size_t)(row0 + m*16 + lr)*DM + k0 + lg*8);
    #pragma unroll
    for (int n=0;n<4;n++)
      b[n] = *(const short8*)(Wb + (size_t)(col0 + n*16 + lr)*DM + k0 + lg*8);
    #pragma unroll
    for (int m=0;m<2;m++)
      #pragma unroll
      for (int n=0;n<4;n++)
        acc[m][n] = __builtin_amdgcn_mfma_f32_16x16x32_bf16(a[m], b[n], acc[m][n], 0,0,0);
  }
  #pragma unroll
  for (int m=0;m<2;m++)
    #pragma unroll
    for (int n=0;n<4;n++)
      #pragma unroll
      for (int r=0;r<4;r++)
        sOut[(m*16 + lg*4 + r)*SOS + col0 + n*16 + lr] = acc[m][n][r];
  __syncthreads();
  for (int j=0;j<8;j++){
    int rrow = wid*8 + j;
    const float* rp = &sOut[rrow*SOS + lane*4];
    float2 v0 = *(const float2*)(rp);
    float2 v1 = *(const float2*)(rp+2);
    float s = v0.x+v0.y+v1.x+v1.y;
    float ss = v0.x*v0.x+v0.y*v0.y+v1.x*v1.x+v1.y*v1.y;
    #pragma unroll
    for (int o=32;o>0;o>>=1){ s += __shfl_xor(s,o,64); ss += __shfl_xor(ss,o,64); }
    if (lane==0){ float m=s*(1.f/DM); sm[rrow]=m; sr[rrow]=rsqrtf(ss*(1.f/DM)-m*m+1e-5f); }
  }
  __syncthreads();
  float gv = pg[tid], bv = pb[tid];
  for (int rrow=0;rrow<32;rrow++){
    int tok = row0 + rrow;
    float v = (sOut[rrow*SOS + tid]-sm[rrow])*sr[rrow]*gv + bv + skip[(size_t)tok*DM + tid];
    out[(size_t)tok*DM + tid] = v;
  }
}

extern "C" void kernel_launch(void* const* d_in, const int* in_sizes, int n_in,
                              void* d_out, int out_size, void* d_ws, size_t ws_size,
                              hipStream_t stream)
{
  const float* input      = (const float*)d_in[0];
  const float* norm_g     = (const float*)d_in[1];
  const float* norm_b     = (const float*)d_in[2];
  const float* in_proj_w  = (const float*)d_in[3];
  const float* conv_w     = (const float*)d_in[4];
  const float* conv_b     = (const float*)d_in[5];
  const float* xproj_w    = (const float*)d_in[6];
  const float* dtproj_w   = (const float*)d_in[7];
  const float* dtproj_b   = (const float*)d_in[8];
  const float* A_log      = (const float*)d_in[9];
  const float* Dp         = (const float*)d_in[10];
  const float* conv_w_b   = (const float*)d_in[11];
  const float* conv_b_b   = (const float*)d_in[12];
  const float* xproj_w_b  = (const float*)d_in[13];
  const float* dtproj_w_b = (const float*)d_in[14];
  const float* dtproj_b_b = (const float*)d_in[15];
  const float* A_log_b    = (const float*)d_in[16];
  const float* Dp_b       = (const float*)d_in[17];
  const float* out_norm_g = (const float*)d_in[18];
  const float* out_norm_b = (const float*)d_in[19];
  const float* out_proj_w = (const float*)d_in[20];
  const float* post_norm_g= (const float*)d_in[21];
  const float* post_norm_b= (const float*)d_in[22];
  float* out = (float*)d_out;

  float* ws = (float*)d_ws;
  const size_t M2 = (size_t)NTOK*DM;           // 2,097,152 elements
  const size_t SCH = (size_t)BT*NCHK*DM*NS;    // 1,048,576 floats (4 MB)
  // slot0 (8MB): xin fp32, later y_f
  float* xin = ws;
  float* yf  = xin;
  // slot1 (8MB): zb bf16 (4MB) + aux weights bf16 (4MB)
  unsigned short* zbuf = (unsigned short*)(ws + M2);
  unsigned short* aux  = (unsigned short*)(ws + M2 + M2/2);   // Wbf / Wcatb / Woutb
  // slot2 (8MB): y_b fp32
  float* yb = ws + 2*M2;
  // slot3 (8MB): dt bf16 fwd+bwd
  unsigned short* dt16f = (unsigned short*)(ws + 3*M2);
  unsigned short* dt16b = dt16f + M2;
  // slot4 (8MB): u bf16 fwd+bwd
  unsigned short* ufb = (unsigned short*)(ws + 4*M2);
  unsigned short* ubb = ufb + M2;
  // slot5: bm/cm (2MB) then ap/hs (16MB)
  float* p   = ws + 5*M2;
  float* bmf = p;              p += (size_t)NTOK*NS;
  float* cmf = p;              p += (size_t)NTOK*NS;
  float* bmb = p;              p += (size_t)NTOK*NS;
  float* cmb = p;              p += (size_t)NTOK*NS;
  float* apf = p;              p += SCH;
  float* hsf = p;              p += SCH;
  float* apb = p;              p += SCH;
  float* hsb = p;              p += SCH;
  // bf16 staging aliases within apf (4MB), dead around their uses:
  unsigned short* xlbf = (unsigned short*)apf;   // live lncvt..inproj, before scan1
  unsigned short* ybf  = (unsigned short*)apf;   // live ycvt..final (apf dead after scan2)

  k_lncvt<<<NTOK/4, 256, 0, stream>>>(input, norm_g, norm_b, xlbf);
  k_wcvt<<<(2*DM*DM)/1024, 256, 0, stream>>>(in_proj_w, aux);
  k_inproj_mfma<<<dim3(NTOK/128, 8, 1), 256, 0, stream>>>(xlbf, aux, xin, zbuf);
  k_conv<<<dim3(SQ/16, BT, 2), 256, 0, stream>>>(xin, conv_w, conv_b, conv_w_b, conv_b_b,
                                                 ufb, ubb);
  k_wcat<<<dim3(4, 2), 256, 0, stream>>>(xproj_w, xproj_w_b, dtproj_w, dtproj_w_b, aux);
  k_xproj_mfma<<<dim3(NTOK/128, 5, 2), 256, 0, stream>>>(ufb, ubb, aux,
                                                         dtproj_b, dtproj_b_b,
                                                         dt16f, dt16b, bmf, cmf, bmb, cmb);
  k_scan1<<<dim3(NCHK, BT, 2), 256, 0, stream>>>(dt16f, dt16b, ufb, ubb, bmf, bmb,
                                                 A_log, A_log_b, apf, hsf, apb, hsb);
  k_scan2<<<256, 64, 0, stream>>>(apf, hsf, apb, hsb);
  k_wcvt<<<(DM*DM)/1024, 256, 0, stream>>>(out_proj_w, aux);
  k_scan3<<<dim3(NCHK, BT, 2), 256, 0, stream>>>(dt16f, dt16b, ufb, ubb, bmf, bmb, cmf, cmb,
                                                 A_log, A_log_b, Dp, Dp_b, zbuf, hsf, hsb,
                                                 yf, yb);
  k_ycvt<<<NTOK/4, 256, 0, stream>>>(yf, yb, out_norm_g, out_norm_b, ybf);
  k_final_mfma<<<NTOK/32, 256, 0, stream>>>(ybf, aux, post_norm_g, post_norm_b, input, out);
}

// Round 7
// 144.615 us; speedup vs baseline: 1.2975x; 1.1109x over previous
//
#include <hip/hip_runtime.h>
#include <math.h>

#define DM 256
#define SQ 4096
#define BT 2
#define NS 16
#define NTOK (BT*SQ)
#define NCHK 128
#define CHL (SQ/NCHK)

typedef __attribute__((ext_vector_type(8))) short short8;
typedef __attribute__((ext_vector_type(4))) float f32x4;

__device__ __forceinline__ float sigm_(float x){ return 1.f/(1.f+__expf(-x)); }
__device__ __forceinline__ float silu_(float x){ return x*sigm_(x); }
__device__ __forceinline__ float softplus_(float x){ return (x>20.f)? x : log1pf(__expf(x)); }
__device__ __forceinline__ unsigned short f2bf(float f){
  unsigned int u = __float_as_uint(f);
  unsigned int r = (u + 0x7FFFu + ((u>>16)&1u)) >> 16;
  return (unsigned short)r;
}
__device__ __forceinline__ float bf2f(unsigned short u){
  return __uint_as_float(((unsigned int)u)<<16);
}

// ---------- prep: LN+cvt of x (blocks 0..2047) | in_proj W cvt (2048..2175)
//            | Wcat build (2176..2183) | out_proj W cvt (2184..2247) ----------
__global__ __launch_bounds__(256) void k_prep(
    const float* __restrict__ x, const float* __restrict__ g, const float* __restrict__ nb,
    unsigned short* __restrict__ xl,
    const float* __restrict__ Win, unsigned short* __restrict__ Wbin,
    const float* __restrict__ xw_f, const float* __restrict__ xw_b,
    const float* __restrict__ dtw_f, const float* __restrict__ dtw_b,
    unsigned short* __restrict__ Wcatb,
    const float* __restrict__ Wout, unsigned short* __restrict__ Wbout)
{
  int bx = blockIdx.x;
  int tid = threadIdx.x;
  if (bx < NTOK/4){
    int tok = bx*4 + (tid>>6);
    int lane = tid & 63;
    const float* row = x + (size_t)tok*DM;
    float4 v = *(const float4*)(row + lane*4);
    float s = v.x+v.y+v.z+v.w;
    float ss = v.x*v.x+v.y*v.y+v.z*v.z+v.w*v.w;
    #pragma unroll
    for (int o=32;o>0;o>>=1){ s += __shfl_xor(s,o,64); ss += __shfl_xor(ss,o,64); }
    float m = s*(1.f/DM);
    float r = rsqrtf(ss*(1.f/DM)-m*m+1e-5f);
    float4 gv = *(const float4*)(g + lane*4);
    float4 bv = *(const float4*)(nb + lane*4);
    ushort4 o4;
    o4.x = f2bf((v.x-m)*r*gv.x+bv.x);
    o4.y = f2bf((v.y-m)*r*gv.y+bv.y);
    o4.z = f2bf((v.z-m)*r*gv.z+bv.z);
    o4.w = f2bf((v.w-m)*r*gv.w+bv.w);
    *(ushort4*)(xl + (size_t)tok*DM + lane*4) = o4;
  } else if (bx < NTOK/4 + 128){
    int i = ((bx - NTOK/4)*256 + tid)*4;
    float4 v = *(const float4*)(Win + i);
    ushort4 o4; o4.x=f2bf(v.x); o4.y=f2bf(v.y); o4.z=f2bf(v.z); o4.w=f2bf(v.w);
    *(ushort4*)(Wbin + i) = o4;
  } else if (bx < NTOK/4 + 136){
    int idx = bx - (NTOK/4 + 128);
    int dir = idx >> 2;
    int kc = (idx & 3)*64;
    const float* xw  = dir? xw_b : xw_f;
    const float* dtw = dir? dtw_b : dtw_f;
    int d = tid;
    float dw[16];
    #pragma unroll
    for (int r=0;r<16;r++) dw[r] = dtw[d*16+r];
    unsigned short* Wd = Wcatb + (size_t)dir*320*DM + (size_t)d*DM + kc;
    for (int kk=0;kk<64;kk++){
      float acc = 0.f;
      #pragma unroll
      for (int r=0;r<16;r++) acc += dw[r]*xw[r*DM + kc + kk];
      Wd[kk] = f2bf(acc);
    }
    if (d < 64){
      unsigned short* Wr = Wcatb + (size_t)dir*320*DM + (size_t)(256+d)*DM + kc;
      if (d < 32){
        const float* src = xw + (size_t)(16+d)*DM + kc;
        for (int kk=0;kk<64;kk++) Wr[kk] = f2bf(src[kk]);
      } else {
        for (int kk=0;kk<64;kk++) Wr[kk] = 0;
      }
    }
  } else {
    int i = ((bx - (NTOK/4 + 136))*256 + tid)*4;
    float4 v = *(const float4*)(Wout + i);
    ushort4 o4; o4.x=f2bf(v.x); o4.y=f2bf(v.y); o4.z=f2bf(v.z); o4.w=f2bf(v.w);
    *(ushort4*)(Wbout + i) = o4;
  }
}

// ---------- in_proj via MFMA: [8192][512] = xl @ Wb^T -> xin fp32 | z bf16 ----------
__global__ __launch_bounds__(256) void k_inproj_mfma(
    const unsigned short* __restrict__ xl, const unsigned short* __restrict__ Wb,
    float* __restrict__ xin, unsigned short* __restrict__ zb)
{
  int tid = threadIdx.x;
  int wid = tid >> 6, lane = tid & 63;
  int wm = wid >> 1, wn = wid & 1;
  int row0 = blockIdx.x*128 + wm*64;
  int col0 = blockIdx.y*64 + wn*32;
  int lr = lane & 15;
  int lg = lane >> 4;
  f32x4 acc[4][2];
  #pragma unroll
  for (int m=0;m<4;m++)
    #pragma unroll
    for (int n=0;n<2;n++) acc[m][n] = (f32x4){0.f,0.f,0.f,0.f};

  #pragma unroll
  for (int k0=0;k0<DM;k0+=32){
    short8 a[4], b[2];
    #pragma unroll
    for (int m=0;m<4;m++)
      a[m] = *(const short8*)(xl + (size_t)(row0 + m*16 + lr)*DM + k0 + lg*8);
    #pragma unroll
    for (int n=0;n<2;n++)
      b[n] = *(const short8*)(Wb + (size_t)(col0 + n*16 + lr)*DM + k0 + lg*8);
    #pragma unroll
    for (int m=0;m<4;m++)
      #pragma unroll
      for (int n=0;n<2;n++)
        acc[m][n] = __builtin_amdgcn_mfma_f32_16x16x32_bf16(a[m], b[n], acc[m][n], 0,0,0);
  }
  if (blockIdx.y < 4){
    #pragma unroll
    for (int m=0;m<4;m++)
      #pragma unroll
      for (int n=0;n<2;n++)
        #pragma unroll
        for (int r=0;r<4;r++){
          int rr = row0 + m*16 + lg*4 + r;
          int cc = col0 + n*16 + lr;
          xin[(size_t)rr*DM + cc] = acc[m][n][r];
        }
  } else {
    int cb = col0 - 256;
    #pragma unroll
    for (int m=0;m<4;m++)
      #pragma unroll
      for (int n=0;n<2;n++)
        #pragma unroll
        for (int r=0;r<4;r++){
          int rr = row0 + m*16 + lg*4 + r;
          int cc = cb + n*16 + lr;
          zb[(size_t)rr*DM + cc] = f2bf(acc[m][n][r]);
        }
  }
}

// ---------- fused fwd+bwd causal dwconv (K=4) + silu -> u bf16 ----------
// block (t0,b): fwd out rows [t0,t0+16), bwd out rows SQ-1-[t0,t0+16); one xin window
__global__ __launch_bounds__(256) void k_conv2(
    const float* __restrict__ xin,
    const float* __restrict__ cw_f, const float* __restrict__ cb_f,
    const float* __restrict__ cw_b, const float* __restrict__ cb_b,
    unsigned short* __restrict__ ufb, unsigned short* __restrict__ ubb)
{
  int d = threadIdx.x;
  int b = blockIdx.y;
  int t0 = blockIdx.x*16;
  float wf0=cw_f[d*4], wf1=cw_f[d*4+1], wf2=cw_f[d*4+2], wf3=cw_f[d*4+3];
  float wb0=cw_b[d*4], wb1=cw_b[d*4+1], wb2=cw_b[d*4+2], wb3=cw_b[d*4+3];
  float bfv = cb_f[d], bbv = cb_b[d];
  const float* xbase = xin + (size_t)b*SQ*DM + d;
  // window r0..r6 = x[t0-3 .. t0+3], out-of-range -> 0
  float r0 = (t0-3>=0)? xbase[(size_t)(t0-3)*DM] : 0.f;
  float r1 = (t0-2>=0)? xbase[(size_t)(t0-2)*DM] : 0.f;
  float r2 = (t0-1>=0)? xbase[(size_t)(t0-1)*DM] : 0.f;
  float r3 = xbase[(size_t)(t0+0)*DM];
  float r4 = xbase[(size_t)(t0+1)*DM];
  float r5 = xbase[(size_t)(t0+2)*DM];
  float r6 = xbase[(size_t)(t0+3)*DM];
  for (int i=0;i<16;i++){
    int t = t0+i;
    // fwd: x[t-3..t] = r0..r3
    float vf = silu_(bfv + wf0*r0 + wf1*r1 + wf2*r2 + wf3*r3);
    ufb[((size_t)b*SQ+t)*DM + d] = f2bf(vf);
    // bwd out row SQ-1-t: wb3*x[t] + wb2*x[t+1] + wb1*x[t+2] + wb0*x[t+3] = r3..r6
    float vb = silu_(bbv + wb3*r3 + wb2*r4 + wb1*r5 + wb0*r6);
    ubb[((size_t)b*SQ+(SQ-1-t))*DM + d] = f2bf(vb);
    // shift window
    r0=r1; r1=r2; r2=r3; r3=r4; r4=r5; r5=r6;
    int tn = t+4;
    r6 = (tn<=SQ-1)? xbase[(size_t)tn*DM] : 0.f;
  }
}

// ---------- xproj+dtproj via MFMA: [8192][320] = u_bf16 @ Wcat^T ----------
__global__ __launch_bounds__(256) void k_xproj_mfma(
    const unsigned short* __restrict__ ufb, const unsigned short* __restrict__ ubb,
    const unsigned short* __restrict__ Wcatb,
    const float* __restrict__ dtbias_f, const float* __restrict__ dtbias_b,
    unsigned short* __restrict__ dt16f, unsigned short* __restrict__ dt16b,
    float* __restrict__ bmf, float* __restrict__ cmf,
    float* __restrict__ bmb, float* __restrict__ cmb)
{
  int dir = blockIdx.z;
  const unsigned short* u  = dir? ubb : ufb;
  const unsigned short* Wc = Wcatb + (size_t)dir*320*DM;
  const float* dbi = dir? dtbias_b : dtbias_f;
  unsigned short* dt = dir? dt16b : dt16f;
  float* bm = dir? bmb : bmf;
  float* cm = dir? cmb : cmf;
  int tid = threadIdx.x;
  int wid = tid >> 6, lane = tid & 63;
  int wm = wid >> 1, wn = wid & 1;
  int row0 = blockIdx.x*128 + wm*64;
  int col0 = blockIdx.y*64 + wn*32;
  int lr = lane & 15, lg = lane >> 4;
  f32x4 acc[4][2];
  #pragma unroll
  for (int m=0;m<4;m++)
    #pragma unroll
    for (int n=0;n<2;n++) acc[m][n] = (f32x4){0.f,0.f,0.f,0.f};
  #pragma unroll
  for (int k0=0;k0<DM;k0+=32){
    short8 a[4], b[2];
    #pragma unroll
    for (int m=0;m<4;m++)
      a[m] = *(const short8*)(u + (size_t)(row0 + m*16 + lr)*DM + k0 + lg*8);
    #pragma unroll
    for (int n=0;n<2;n++)
      b[n] = *(const short8*)(Wc + (size_t)(col0 + n*16 + lr)*DM + k0 + lg*8);
    #pragma unroll
    for (int m=0;m<4;m++)
      #pragma unroll
      for (int n=0;n<2;n++)
        acc[m][n] = __builtin_amdgcn_mfma_f32_16x16x32_bf16(a[m], b[n], acc[m][n], 0,0,0);
  }
  if (blockIdx.y < 4){
    #pragma unroll
    for (int n=0;n<2;n++){
      int cc = col0 + n*16 + lr;
      float bias = dbi[cc];
      #pragma unroll
      for (int m=0;m<4;m++)
        #pragma unroll
        for (int r=0;r<4;r++){
          int rr = row0 + m*16 + lg*4 + r;
          dt[(size_t)rr*DM + cc] = f2bf(softplus_(acc[m][n][r] + bias));
        }
    }
  } else if (wn == 0){
    #pragma unroll
    for (int n=0;n<2;n++){
      float* outp = n ? cm : bm;
      #pragma unroll
      for (int m=0;m<4;m++)
        #pragma unroll
        for (int r=0;r<4;r++){
          int rr = row0 + m*16 + lg*4 + r;
          outp[(size_t)rr*NS + lr] = acc[m][n][r];
        }
    }
  }
}

// ---------- scan phase 1: per-chunk summaries (Aprod, h_end) ----------
__global__ __launch_bounds__(256) void k_scan1(
    const unsigned short* __restrict__ dtf, const unsigned short* __restrict__ dtb,
    const unsigned short* __restrict__ ufb, const unsigned short* __restrict__ ubb,
    const float* __restrict__ bmf, const float* __restrict__ bmb,
    const float* __restrict__ alog_f, const float* __restrict__ alog_b,
    float* __restrict__ apf, float* __restrict__ hsf,
    float* __restrict__ apb, float* __restrict__ hsb)
{
  int c = blockIdx.x, b = blockIdx.y, dir = blockIdx.z;
  const unsigned short* dt = dir? dtb : dtf;
  const unsigned short* u  = dir? ubb : ufb;
  const float* bmp= dir? bmb : bmf;
  const float* al = dir? alog_b : alog_f;
  float* ap = dir? apb : apf;
  float* hs = dir? hsb : hsf;
  int d = threadIdx.x;
  __shared__ float sB[CHL*NS];
  for (int i=threadIdx.x;i<CHL*NS;i+=256) sB[i] = bmp[((size_t)b*SQ + c*CHL)*NS + i];
  float A[NS];
  #pragma unroll
  for (int n=0;n<NS;n++) A[n] = -__expf(al[d*NS+n]);
  float h[NS] = {};
  float dts = 0.f;
  __syncthreads();
  for (int t=0;t<CHL;t++){
    size_t idx = ((size_t)b*SQ + c*CHL + t)*DM + d;
    float dtv = bf2f(dt[idx]);
    float uv  = bf2f(u[idx]);
    float du  = dtv*uv;
    dts += dtv;
    #pragma unroll
    for (int n=0;n<NS;n++) h[n] = h[n]*__expf(dtv*A[n]) + du*sB[t*NS+n];
  }
  size_t o = (((size_t)b*NCHK + c)*DM + d)*NS;
  #pragma unroll
  for (int n=0;n<NS;n++){ hs[o+n] = h[n]; ap[o+n] = __expf(A[n]*dts); }
}

// ---------- scan phase 2: parallel (LDS-staged segmented scan), writes hs = exclusive prefix ----------
__global__ __launch_bounds__(256) void k_scan2(
    float* __restrict__ apf, float* __restrict__ hsf,
    float* __restrict__ apb, float* __restrict__ hsb)
{
  __shared__ float sa[NCHK][64];
  __shared__ float sv[NCHK][64];
  __shared__ float segA[4][64], segV[4][64];
  int bx = blockIdx.x;
  int dg = bx & 63, b = (bx>>6)&1, dir = bx>>7;
  const float* ap = dir? apb : apf;
  float* hs = dir? hsb : hsf;
  int dn = threadIdx.x & 63;
  int cg = threadIdx.x >> 6;          // 0..3: segment of 32 chunks
  size_t base = (size_t)b*NCHK*4096 + dg*64 + dn;
  // load (coalesced 256B per wave-row)
  for (int i=0;i<32;i++){
    int c = cg*32 + i;
    size_t idx = base + (size_t)c*4096;
    sa[c][dn] = ap[idx];
    sv[c][dn] = hs[idx];
  }
  __syncthreads();
  // phase A: serial affine scan within segment -> (A,V) composition
  float A = 1.f, V = 0.f;
  for (int i=0;i<32;i++){
    int c = cg*32 + i;
    float a = sa[c][dn], v = sv[c][dn];
    V = a*V + v;
    A = A*a;
  }
  segA[cg][dn] = A; segV[cg][dn] = V;
  __syncthreads();
  // phase B: exclusive prefix over segments (cg is wave-uniform)
  float pre = 0.f;
  for (int s=0;s<cg;s++) pre = segA[s][dn]*pre + segV[s][dn];
  // phase C: replay segment, write exclusive prefix
  float xv = pre;
  for (int i=0;i<32;i++){
    int c = cg*32 + i;
    size_t idx = base + (size_t)c*4096;
    hs[idx] = xv;
    float a = sa[c][dn], v = sv[c][dn];
    xv = a*xv + v;
  }
}

// ---------- scan phase 3: replay with prefix, emit y bf16 (both dirs, one dispatch) ----------
__global__ __launch_bounds__(256) void k_scan3(
    const unsigned short* __restrict__ dtf, const unsigned short* __restrict__ dtb,
    const unsigned short* __restrict__ ufb, const unsigned short* __restrict__ ubb,
    const float* __restrict__ bmf, const float* __restrict__ bmb,
    const float* __restrict__ cmf, const float* __restrict__ cmb,
    const float* __restrict__ alf, const float* __restrict__ alb,
    const float* __restrict__ Df, const float* __restrict__ Db,
    const unsigned short* __restrict__ zb,
    const float* __restrict__ hsf, const float* __restrict__ hsb,
    unsigned short* __restrict__ yf, unsigned short* __restrict__ yb)
{
  int c = blockIdx.x, b = blockIdx.y;
  int dir = blockIdx.z;
  const unsigned short* dt = dir? dtb : dtf;
  const unsigned short* u  = dir? ubb : ufb;
  const float* bmp= dir? bmb : bmf;
  const float* cmp= dir? cmb : cmf;
  const float* al = dir? alb : alf;
  const float* Dv = dir? Db  : Df;
  const float* hs = dir? hsb : hsf;
  unsigned short* yout = dir? yb : yf;
  int d = threadIdx.x;
  __shared__ float sB[CHL*NS];
  __shared__ float sC[CHL*NS];
  for (int i=threadIdx.x;i<CHL*NS;i+=256){
    sB[i] = bmp[((size_t)b*SQ + c*CHL)*NS + i];
    sC[i] = cmp[((size_t)b*SQ + c*CHL)*NS + i];
  }
  float A[NS], h[NS];
  size_t o = (((size_t)b*NCHK + c)*DM + d)*NS;
  #pragma unroll
  for (int n=0;n<NS;n++){ A[n] = -__expf(al[d*NS+n]); h[n] = hs[o+n]; }
  float Dd = Dv[d];
  __syncthreads();
  for (int t=0;t<CHL;t++){
    int gt = c*CHL + t;
    size_t idx = ((size_t)b*SQ + gt)*DM + d;
    float dtv = bf2f(dt[idx]);
    float uv  = bf2f(u[idx]);
    float du  = dtv*uv;
    float y = 0.f;
    #pragma unroll
    for (int n=0;n<NS;n++){
      h[n] = h[n]*__expf(dtv*A[n]) + du*sB[t*NS+n];
      y += h[n]*sC[t*NS+n];
    }
    y += uv*Dd;
    int torig = dir ? (SQ-1-gt) : gt;
    size_t oidx = ((size_t)b*SQ + torig)*DM + d;
    float zv = bf2f(zb[oidx]);
    yout[oidx] = f2bf(y * (zv * sigm_(zv)));
  }
}

// ---------- y-combine + out-LN + bf16 convert: one wave per token ----------
__global__ __launch_bounds__(256) void k_ycvt(const unsigned short* __restrict__ yf,
                                              const unsigned short* __restrict__ yb,
                                              const float* __restrict__ og, const float* __restrict__ ob,
                                              unsigned short* __restrict__ ybf){
  int tok = blockIdx.x*4 + (threadIdx.x>>6);
  int lane = threadIdx.x & 63;
  size_t base = (size_t)tok*DM;
  ushort4 hf = *(const ushort4*)(yf + base + lane*4);
  ushort4 hb = *(const ushort4*)(yb + base + lane*4);
  float4 v;
  v.x = 0.5f*(bf2f(hf.x)+bf2f(hb.x));
  v.y = 0.5f*(bf2f(hf.y)+bf2f(hb.y));
  v.z = 0.5f*(bf2f(hf.z)+bf2f(hb.z));
  v.w = 0.5f*(bf2f(hf.w)+bf2f(hb.w));
  float s = v.x+v.y+v.z+v.w;
  float ss = v.x*v.x+v.y*v.y+v.z*v.z+v.w*v.w;
  #pragma unroll
  for (int o=32;o>0;o>>=1){ s += __shfl_xor(s,o,64); ss += __shfl_xor(ss,o,64); }
  float m = s*(1.f/DM);
  float r = rsqrtf(ss*(1.f/DM)-m*m+1e-5f);
  float4 gv = *(const float4*)(og + lane*4);
  float4 bv = *(const float4*)(ob + lane*4);
  ushort4 o4;
  o4.x = f2bf((v.x-m)*r*gv.x+bv.x);
  o4.y = f2bf((v.y-m)*r*gv.y+bv.y);
  o4.z = f2bf((v.z-m)*r*gv.z+bv.z);
  o4.w = f2bf((v.w-m)*r*gv.w+bv.w);
  *(ushort4*)(ybf + base + lane*4) = o4;
}

// ---------- final via MFMA: C[8192][256] = ybf @ Woutb^T, post-LN + skip ----------
#define SOS 266
__global__ __launch_bounds__(256) void k_final_mfma(
    const unsigned short* __restrict__ ybf, const unsigned short* __restrict__ Wb,
    const float* __restrict__ pg, const float* __restrict__ pb,
    const float* __restrict__ skip, float* __restrict__ out)
{
  __shared__ float sOut[32*SOS];
  __shared__ float sm[32], sr[32];
  int tid = threadIdx.x;
  int wid = tid >> 6, lane = tid & 63;
  int lr = lane & 15, lg = lane >> 4;
  int row0 = blockIdx.x*32;
  int col0 = wid*64;
  f32x4 acc[2][4];
  #pragma unroll
  for (int m=0;m<2;m++)
    #pragma unroll
    for (int n=0;n<4;n++) acc[m][n] = (f32x4){0.f,0.f,0.f,0.f};
  #pragma unroll
  for (int k0=0;k0<DM;k0+=32){
    short8 a[2], b[4];
    #pragma unroll
    for (int m=0;m<2;m++)
      a[m] = *(const short8*)(ybf + (size_t)(row0 + m*16 + lr)*DM + k0 + lg*8);
    #pragma unroll
    for (int n=0;n<4;n++)
      b[n] = *(const short8*)(Wb + (size_t)(col0 + n*16 + lr)*DM + k0 + lg*8);
    #pragma unroll
    for (int m=0;m<2;m++)
      #pragma unroll
      for (int n=0;n<4;n++)
        acc[m][n] = __builtin_amdgcn_mfma_f32_16x16x32_bf16(a[m], b[n], acc[m][n], 0,0,0);
  }
  #pragma unroll
  for (int m=0;m<2;m++)
    #pragma unroll
    for (int n=0;n<4;n++)
      #pragma unroll
      for (int r=0;r<4;r++)
        sOut[(m*16 + lg*4 + r)*SOS + col0 + n*16 + lr] = acc[m][n][r];
  __syncthreads();
  for (int j=0;j<8;j++){
    int rrow = wid*8 + j;
    const float* rp = &sOut[rrow*SOS + lane*4];
    float2 v0 = *(const float2*)(rp);
    float2 v1 = *(const float2*)(rp+2);
    float s = v0.x+v0.y+v1.x+v1.y;
    float ss = v0.x*v0.x+v0.y*v0.y+v1.x*v1.x+v1.y*v1.y;
    #pragma unroll
    for (int o=32;o>0;o>>=1){ s += __shfl_xor(s,o,64); ss += __shfl_xor(ss,o,64); }
    if (lane==0){ float m=s*(1.f/DM); sm[rrow]=m; sr[rrow]=rsqrtf(ss*(1.f/DM)-m*m+1e-5f); }
  }
  __syncthreads();
  float gv = pg[tid], bv = pb[tid];
  for (int rrow=0;rrow<32;rrow++){
    int tok = row0 + rrow;
    float v = (sOut[rrow*SOS + tid]-sm[rrow])*sr[rrow]*gv + bv + skip[(size_t)tok*DM + tid];
    out[(size_t)tok*DM + tid] = v;
  }
}

extern "C" void kernel_launch(void* const* d_in, const int* in_sizes, int n_in,
                              void* d_out, int out_size, void* d_ws, size_t ws_size,
                              hipStream_t stream)
{
  const float* input      = (const float*)d_in[0];
  const float* norm_g     = (const float*)d_in[1];
  const float* norm_b     = (const float*)d_in[2];
  const float* in_proj_w  = (const float*)d_in[3];
  const float* conv_w     = (const float*)d_in[4];
  const float* conv_b     = (const float*)d_in[5];
  const float* xproj_w    = (const float*)d_in[6];
  const float* dtproj_w   = (const float*)d_in[7];
  const float* dtproj_b   = (const float*)d_in[8];
  const float* A_log      = (const float*)d_in[9];
  const float* Dp         = (const float*)d_in[10];
  const float* conv_w_b   = (const float*)d_in[11];
  const float* conv_b_b   = (const float*)d_in[12];
  const float* xproj_w_b  = (const float*)d_in[13];
  const float* dtproj_w_b = (const float*)d_in[14];
  const float* dtproj_b_b = (const float*)d_in[15];
  const float* A_log_b    = (const float*)d_in[16];
  const float* Dp_b       = (const float*)d_in[17];
  const float* out_norm_g = (const float*)d_in[18];
  const float* out_norm_b = (const float*)d_in[19];
  const float* out_proj_w = (const float*)d_in[20];
  const float* post_norm_g= (const float*)d_in[21];
  const float* post_norm_b= (const float*)d_in[22];
  float* out = (float*)d_out;

  float* ws = (float*)d_ws;
  const size_t M2 = (size_t)NTOK*DM;           // 2,097,152 elements
  const size_t SCH = (size_t)BT*NCHK*DM*NS;    // 1,048,576 floats (4 MB)
  // slot0 (8MB): xin fp32 (inproj->conv); later yf/yb bf16 (scan3->ycvt)
  float* xin = ws;
  unsigned short* y16f = (unsigned short*)ws;         // 4MB
  unsigned short* y16b = (unsigned short*)ws + M2;    // 4MB
  // slot1 (8MB): zb bf16 (4MB) + weight staging (4MB)
  unsigned short* zbuf = (unsigned short*)(ws + M2);
  unsigned short* auxw = (unsigned short*)(ws + M2 + M2/2);
  unsigned short* Wbin  = auxw;                    // 512*256  = 131072 u16 (256KB)
  unsigned short* Wcatb = auxw + 131072;           // 2*320*256 = 163840 u16 (320KB)
  unsigned short* Wbout = auxw + 131072 + 163840;  // 256*256  = 65536 u16 (128KB)
  // slot2 (8MB): free (kept for layout stability)
  // slot3 (8MB): dt bf16 fwd+bwd
  unsigned short* dt16f = (unsigned short*)(ws + 3*M2);
  unsigned short* dt16b = dt16f + M2;
  // slot4 (8MB): u bf16 fwd+bwd
  unsigned short* ufb = (unsigned short*)(ws + 4*M2);
  unsigned short* ubb = ufb + M2;
  // slot5: bm/cm (2MB) then ap/hs (16MB)
  float* p   = ws + 5*M2;
  float* bmf = p;              p += (size_t)NTOK*NS;
  float* cmf = p;              p += (size_t)NTOK*NS;
  float* bmb = p;              p += (size_t)NTOK*NS;
  float* cmb = p;              p += (size_t)NTOK*NS;
  float* apf = p;              p += SCH;
  float* hsf = p;              p += SCH;
  float* apb = p;              p += SCH;
  float* hsb = p;              p += SCH;
  // bf16 staging aliases within apf (4MB):
  unsigned short* xlbf = (unsigned short*)apf;   // live prep..inproj (before scan1)
  unsigned short* ybf  = (unsigned short*)apf;   // live ycvt..final (ap dead after scan2)

  k_prep<<<NTOK/4 + 136 + 64, 256, 0, stream>>>(input, norm_g, norm_b, xlbf,
                                                in_proj_w, Wbin,
                                                xproj_w, xproj_w_b, dtproj_w, dtproj_w_b, Wcatb,
                                                out_proj_w, Wbout);
  k_inproj_mfma<<<dim3(NTOK/128, 8, 1), 256, 0, stream>>>(xlbf, Wbin, xin, zbuf);
  k_conv2<<<dim3(SQ/16, BT), 256, 0, stream>>>(xin, conv_w, conv_b, conv_w_b, conv_b_b,
                                               ufb, ubb);
  k_xproj_mfma<<<dim3(NTOK/128, 5, 2), 256, 0, stream>>>(ufb, ubb, Wcatb,
                                                         dtproj_b, dtproj_b_b,
                                                         dt16f, dt16b, bmf, cmf, bmb, cmb);
  k_scan1<<<dim3(NCHK, BT, 2), 256, 0, stream>>>(dt16f, dt16b, ufb, ubb, bmf, bmb,
                                                 A_log, A_log_b, apf, hsf, apb, hsb);
  k_scan2<<<256, 256, 0, stream>>>(apf, hsf, apb, hsb);
  k_scan3<<<dim3(NCHK, BT, 2), 256, 0, stream>>>(dt16f, dt16b, ufb, ubb, bmf, bmb, cmf, cmb,
                                                 A_log, A_log_b, Dp, Dp_b, zbuf, hsf, hsb,
                                                 y16f, y16b);
  k_ycvt<<<NTOK/4, 256, 0, stream>>>(y16f, y16b, out_norm_g, out_norm_b, ybf);
  k_final_mfma<<<NTOK/32, 256, 0, stream>>>(ybf, Wbout, post_norm_g, post_norm_b, input, out);
}

// Round 8
// 144.416 us; speedup vs baseline: 1.2993x; 1.0014x over previous
//
#include <hip/hip_runtime.h>
#include <math.h>

#define DM 256
#define SQ 4096
#define BT 2
#define NS 16
#define NTOK (BT*SQ)
#define NCHK 128
#define CHL (SQ/NCHK)

typedef __attribute__((ext_vector_type(8))) short short8;
typedef __attribute__((ext_vector_type(4))) float f32x4;

__device__ __forceinline__ float sigm_(float x){ return 1.f/(1.f+__expf(-x)); }
__device__ __forceinline__ float silu_(float x){ return x*sigm_(x); }
__device__ __forceinline__ float softplus_(float x){ return (x>20.f)? x : log1pf(__expf(x)); }
__device__ __forceinline__ unsigned short f2bf(float f){
  unsigned int u = __float_as_uint(f);
  unsigned int r = (u + 0x7FFFu + ((u>>16)&1u)) >> 16;
  return (unsigned short)r;
}
__device__ __forceinline__ float bf2f(unsigned short u){
  return __uint_as_float(((unsigned int)u)<<16);
}

// ---------- prep: LN+cvt of x (blocks 0..2047) | in_proj W cvt (2048..2175)
//            | Wcat build (2176..2183) | out_proj W cvt (2184..2247) ----------
__global__ __launch_bounds__(256) void k_prep(
    const float* __restrict__ x, const float* __restrict__ g, const float* __restrict__ nb,
    unsigned short* __restrict__ xl,
    const float* __restrict__ Win, unsigned short* __restrict__ Wbin,
    const float* __restrict__ xw_f, const float* __restrict__ xw_b,
    const float* __restrict__ dtw_f, const float* __restrict__ dtw_b,
    unsigned short* __restrict__ Wcatb,
    const float* __restrict__ Wout, unsigned short* __restrict__ Wbout)
{
  int bx = blockIdx.x;
  int tid = threadIdx.x;
  if (bx < NTOK/4){
    int tok = bx*4 + (tid>>6);
    int lane = tid & 63;
    const float* row = x + (size_t)tok*DM;
    float4 v = *(const float4*)(row + lane*4);
    float s = v.x+v.y+v.z+v.w;
    float ss = v.x*v.x+v.y*v.y+v.z*v.z+v.w*v.w;
    #pragma unroll
    for (int o=32;o>0;o>>=1){ s += __shfl_xor(s,o,64); ss += __shfl_xor(ss,o,64); }
    float m = s*(1.f/DM);
    float r = rsqrtf(ss*(1.f/DM)-m*m+1e-5f);
    float4 gv = *(const float4*)(g + lane*4);
    float4 bv = *(const float4*)(nb + lane*4);
    ushort4 o4;
    o4.x = f2bf((v.x-m)*r*gv.x+bv.x);
    o4.y = f2bf((v.y-m)*r*gv.y+bv.y);
    o4.z = f2bf((v.z-m)*r*gv.z+bv.z);
    o4.w = f2bf((v.w-m)*r*gv.w+bv.w);
    *(ushort4*)(xl + (size_t)tok*DM + lane*4) = o4;
  } else if (bx < NTOK/4 + 128){
    int i = ((bx - NTOK/4)*256 + tid)*4;
    float4 v = *(const float4*)(Win + i);
    ushort4 o4; o4.x=f2bf(v.x); o4.y=f2bf(v.y); o4.z=f2bf(v.z); o4.w=f2bf(v.w);
    *(ushort4*)(Wbin + i) = o4;
  } else if (bx < NTOK/4 + 136){
    int idx = bx - (NTOK/4 + 128);
    int dir = idx >> 2;
    int kc = (idx & 3)*64;
    const float* xw  = dir? xw_b : xw_f;
    const float* dtw = dir? dtw_b : dtw_f;
    int d = tid;
    float dw[16];
    #pragma unroll
    for (int r=0;r<16;r++) dw[r] = dtw[d*16+r];
    unsigned short* Wd = Wcatb + (size_t)dir*320*DM + (size_t)d*DM + kc;
    for (int kk=0;kk<64;kk++){
      float acc = 0.f;
      #pragma unroll
      for (int r=0;r<16;r++) acc += dw[r]*xw[r*DM + kc + kk];
      Wd[kk] = f2bf(acc);
    }
    if (d < 64){
      unsigned short* Wr = Wcatb + (size_t)dir*320*DM + (size_t)(256+d)*DM + kc;
      if (d < 32){
        const float* src = xw + (size_t)(16+d)*DM + kc;
        for (int kk=0;kk<64;kk++) Wr[kk] = f2bf(src[kk]);
      } else {
        for (int kk=0;kk<64;kk++) Wr[kk] = 0;
      }
    }
  } else {
    int i = ((bx - (NTOK/4 + 136))*256 + tid)*4;
    float4 v = *(const float4*)(Wout + i);
    ushort4 o4; o4.x=f2bf(v.x); o4.y=f2bf(v.y); o4.z=f2bf(v.z); o4.w=f2bf(v.w);
    *(ushort4*)(Wbout + i) = o4;
  }
}

// ---------- in_proj MFMA + fused causal dwconv+silu (y<4) | z bf16 (y>=4) ----------
// y<4 block: 128 tokens x 64 cols of xin in LDS + 3-token halos -> u fwd/bwd bf16
__global__ __launch_bounds__(256) void k_inproj_conv(
    const unsigned short* __restrict__ xl, const unsigned short* __restrict__ Wb,
    const float* __restrict__ cw_f, const float* __restrict__ cb_f,
    const float* __restrict__ cw_b, const float* __restrict__ cb_b,
    unsigned short* __restrict__ ufb, unsigned short* __restrict__ ubb,
    unsigned short* __restrict__ zb)
{
  __shared__ float xs[134][68];           // rows: 0..2 fwd halo, 3..130 main, 131..133 bwd halo
  __shared__ unsigned short xh[6][256];   // staged xl halo rows
  int tid = threadIdx.x;
  int wid = tid >> 6, lane = tid & 63;
  int wm = wid >> 1, wn = wid & 1;
  int row0 = blockIdx.x*128 + wm*64;
  int col0 = blockIdx.y*64 + wn*32;
  int lr = lane & 15, lg = lane >> 4;
  f32x4 acc[4][2];
  #pragma unroll
  for (int m=0;m<4;m++)
    #pragma unroll
    for (int n=0;n<2;n++) acc[m][n] = (f32x4){0.f,0.f,0.f,0.f};

  #pragma unroll
  for (int k0=0;k0<DM;k0+=32){
    short8 a[4], b[2];
    #pragma unroll
    for (int m=0;m<4;m++)
      a[m] = *(const short8*)(xl + (size_t)(row0 + m*16 + lr)*DM + k0 + lg*8);
    #pragma unroll
    for (int n=0;n<2;n++)
      b[n] = *(const short8*)(Wb + (size_t)(col0 + n*16 + lr)*DM + k0 + lg*8);
    #pragma unroll
    for (int m=0;m<4;m++)
      #pragma unroll
      for (int n=0;n<2;n++)
        acc[m][n] = __builtin_amdgcn_mfma_f32_16x16x32_bf16(a[m], b[n], acc[m][n], 0,0,0);
  }
  if (blockIdx.y >= 4){
    int cb = col0 - 256;
    #pragma unroll
    for (int m=0;m<4;m++)
      #pragma unroll
      for (int n=0;n<2;n++)
        #pragma unroll
        for (int r=0;r<4;r++){
          int rr = row0 + m*16 + lg*4 + r;
          int cc = cb + n*16 + lr;
          zb[(size_t)rr*DM + cc] = f2bf(acc[m][n][r]);
        }
    return;
  }
  // park xin tile in LDS (+3 row offset for halo)
  #pragma unroll
  for (int m=0;m<4;m++)
    #pragma unroll
    for (int n=0;n<2;n++)
      #pragma unroll
      for (int r=0;r<4;r++)
        xs[wm*64 + m*16 + lg*4 + r + 3][wn*32 + n*16 + lr] = acc[m][n][r];
  // stage halo xl rows (zeros outside sequence)
  int b_  = blockIdx.x >> 5;
  int lt0 = (blockIdx.x & 31)*128;
  for (int i=tid; i<6*256; i+=256){
    int hr = i >> 8, k = i & 255;
    int lt = (hr<3)? (lt0-3+hr) : (lt0+128+(hr-3));
    unsigned short v = 0;
    if (lt >= 0 && lt < SQ) v = xl[((size_t)b_*SQ+lt)*DM + k];
    xh[hr][k] = v;
  }
  __syncthreads();
  // halo xin values: 6 rows x 64 cols direct dot
  for (int i=tid; i<384; i+=256){
    int hr = i >> 6, col = i & 63;
    int gcol = blockIdx.y*64 + col;
    float acch = 0.f;
    for (int k=0;k<256;k+=8){
      short8 xa = *(const short8*)&xh[hr][k];
      short8 wv = *(const short8*)(Wb + (size_t)gcol*DM + k);
      #pragma unroll
      for (int e=0;e<8;e++) acch += bf2f((unsigned short)xa[e])*bf2f((unsigned short)wv[e]);
    }
    int xr = (hr<3)? hr : (131 + hr - 3);
    xs[xr][col] = acch;
  }
  __syncthreads();
  // depthwise conv K=4 + silu, both directions, from LDS
  int col = tid & 63, tg = tid >> 6;
  int gd = blockIdx.y*64 + col;
  float wf0=cw_f[gd*4], wf1=cw_f[gd*4+1], wf2=cw_f[gd*4+2], wf3=cw_f[gd*4+3];
  float wb0=cw_b[gd*4], wb1=cw_b[gd*4+1], wb2=cw_b[gd*4+2], wb3=cw_b[gd*4+3];
  float bfv = cb_f[gd], bbv = cb_b[gd];
  for (int i=0;i<32;i++){
    int r = tg*32 + i;                       // local token in tile
    float x0=xs[r][col], x1=xs[r+1][col], x2=xs[r+2][col], x3=xs[r+3][col];
    float vf = silu_(bfv + wf0*x0 + wf1*x1 + wf2*x2 + wf3*x3);
    ufb[((size_t)b_*SQ + lt0 + r)*DM + gd] = f2bf(vf);
    float x4=xs[r+4][col], x5=xs[r+5][col], x6=xs[r+6][col];
    float vb = silu_(bbv + wb3*x3 + wb2*x4 + wb1*x5 + wb0*x6);
    ubb[((size_t)b_*SQ + (SQ-1-(lt0+r)))*DM + gd] = f2bf(vb);
  }
}

// ---------- xproj+dtproj via MFMA: [8192][320] = u_bf16 @ Wcat^T ----------
__global__ __launch_bounds__(256) void k_xproj_mfma(
    const unsigned short* __restrict__ ufb, const unsigned short* __restrict__ ubb,
    const unsigned short* __restrict__ Wcatb,
    const float* __restrict__ dtbias_f, const float* __restrict__ dtbias_b,
    unsigned short* __restrict__ dt16f, unsigned short* __restrict__ dt16b,
    float* __restrict__ bmf, float* __restrict__ cmf,
    float* __restrict__ bmb, float* __restrict__ cmb)
{
  int dir = blockIdx.z;
  const unsigned short* u  = dir? ubb : ufb;
  const unsigned short* Wc = Wcatb + (size_t)dir*320*DM;
  const float* dbi = dir? dtbias_b : dtbias_f;
  unsigned short* dt = dir? dt16b : dt16f;
  float* bm = dir? bmb : bmf;
  float* cm = dir? cmb : cmf;
  int tid = threadIdx.x;
  int wid = tid >> 6, lane = tid & 63;
  int wm = wid >> 1, wn = wid & 1;
  int row0 = blockIdx.x*128 + wm*64;
  int col0 = blockIdx.y*64 + wn*32;
  int lr = lane & 15, lg = lane >> 4;
  f32x4 acc[4][2];
  #pragma unroll
  for (int m=0;m<4;m++)
    #pragma unroll
    for (int n=0;n<2;n++) acc[m][n] = (f32x4){0.f,0.f,0.f,0.f};
  #pragma unroll
  for (int k0=0;k0<DM;k0+=32){
    short8 a[4], b[2];
    #pragma unroll
    for (int m=0;m<4;m++)
      a[m] = *(const short8*)(u + (size_t)(row0 + m*16 + lr)*DM + k0 + lg*8);
    #pragma unroll
    for (int n=0;n<2;n++)
      b[n] = *(const short8*)(Wc + (size_t)(col0 + n*16 + lr)*DM + k0 + lg*8);
    #pragma unroll
    for (int m=0;m<4;m++)
      #pragma unroll
      for (int n=0;n<2;n++)
        acc[m][n] = __builtin_amdgcn_mfma_f32_16x16x32_bf16(a[m], b[n], acc[m][n], 0,0,0);
  }
  if (blockIdx.y < 4){
    #pragma unroll
    for (int n=0;n<2;n++){
      int cc = col0 + n*16 + lr;
      float bias = dbi[cc];
      #pragma unroll
      for (int m=0;m<4;m++)
        #pragma unroll
        for (int r=0;r<4;r++){
          int rr = row0 + m*16 + lg*4 + r;
          dt[(size_t)rr*DM + cc] = f2bf(softplus_(acc[m][n][r] + bias));
        }
    }
  } else if (wn == 0){
    #pragma unroll
    for (int n=0;n<2;n++){
      float* outp = n ? cm : bm;
      #pragma unroll
      for (int m=0;m<4;m++)
        #pragma unroll
        for (int r=0;r<4;r++){
          int rr = row0 + m*16 + lg*4 + r;
          outp[(size_t)rr*NS + lr] = acc[m][n][r];
        }
    }
  }
}

// ---------- scan phase 1: per-chunk summaries (Aprod, h_end) ----------
__global__ __launch_bounds__(256) void k_scan1(
    const unsigned short* __restrict__ dtf, const unsigned short* __restrict__ dtb,
    const unsigned short* __restrict__ ufb, const unsigned short* __restrict__ ubb,
    const float* __restrict__ bmf, const float* __restrict__ bmb,
    const float* __restrict__ alog_f, const float* __restrict__ alog_b,
    float* __restrict__ apf, float* __restrict__ hsf,
    float* __restrict__ apb, float* __restrict__ hsb)
{
  int c = blockIdx.x, b = blockIdx.y, dir = blockIdx.z;
  const unsigned short* dt = dir? dtb : dtf;
  const unsigned short* u  = dir? ubb : ufb;
  const float* bmp= dir? bmb : bmf;
  const float* al = dir? alog_b : alog_f;
  float* ap = dir? apb : apf;
  float* hs = dir? hsb : hsf;
  int d = threadIdx.x;
  __shared__ float sB[CHL*NS];
  for (int i=threadIdx.x;i<CHL*NS;i+=256) sB[i] = bmp[((size_t)b*SQ + c*CHL)*NS + i];
  float A[NS];
  #pragma unroll
  for (int n=0;n<NS;n++) A[n] = -__expf(al[d*NS+n]);
  float h[NS] = {};
  float dts = 0.f;
  __syncthreads();
  for (int t=0;t<CHL;t++){
    size_t idx = ((size_t)b*SQ + c*CHL + t)*DM + d;
    float dtv = bf2f(dt[idx]);
    float uv  = bf2f(u[idx]);
    float du  = dtv*uv;
    dts += dtv;
    #pragma unroll
    for (int n=0;n<NS;n++) h[n] = h[n]*__expf(dtv*A[n]) + du*sB[t*NS+n];
  }
  size_t o = (((size_t)b*NCHK + c)*DM + d)*NS;
  #pragma unroll
  for (int n=0;n<NS;n++){ hs[o+n] = h[n]; ap[o+n] = __expf(A[n]*dts); }
}

// ---------- scan phase 2: parallel segmented scan, writes hs = exclusive prefix ----------
__global__ __launch_bounds__(256) void k_scan2(
    float* __restrict__ apf, float* __restrict__ hsf,
    float* __restrict__ apb, float* __restrict__ hsb)
{
  __shared__ float sa[NCHK][64];
  __shared__ float sv[NCHK][64];
  __shared__ float segA[4][64], segV[4][64];
  int bx = blockIdx.x;
  int dg = bx & 63, b = (bx>>6)&1, dir = bx>>7;
  const float* ap = dir? apb : apf;
  float* hs = dir? hsb : hsf;
  int dn = threadIdx.x & 63;
  int cg = threadIdx.x >> 6;
  size_t base = (size_t)b*NCHK*4096 + dg*64 + dn;
  for (int i=0;i<32;i++){
    int c = cg*32 + i;
    size_t idx = base + (size_t)c*4096;
    sa[c][dn] = ap[idx];
    sv[c][dn] = hs[idx];
  }
  __syncthreads();
  float A = 1.f, V = 0.f;
  for (int i=0;i<32;i++){
    int c = cg*32 + i;
    float a = sa[c][dn], v = sv[c][dn];
    V = a*V + v;
    A = A*a;
  }
  segA[cg][dn] = A; segV[cg][dn] = V;
  __syncthreads();
  float pre = 0.f;
  for (int s=0;s<cg;s++) pre = segA[s][dn]*pre + segV[s][dn];
  float xv = pre;
  for (int i=0;i<32;i++){
    int c = cg*32 + i;
    size_t idx = base + (size_t)c*4096;
    hs[idx] = xv;
    float a = sa[c][dn], v = sv[c][dn];
    xv = a*xv + v;
  }
}

// ---------- scan phase 3: replay with prefix, emit y bf16 (both dirs, one dispatch) ----------
__global__ __launch_bounds__(256) void k_scan3(
    const unsigned short* __restrict__ dtf, const unsigned short* __restrict__ dtb,
    const unsigned short* __restrict__ ufb, const unsigned short* __restrict__ ubb,
    const float* __restrict__ bmf, const float* __restrict__ bmb,
    const float* __restrict__ cmf, const float* __restrict__ cmb,
    const float* __restrict__ alf, const float* __restrict__ alb,
    const float* __restrict__ Df, const float* __restrict__ Db,
    const unsigned short* __restrict__ zb,
    const float* __restrict__ hsf, const float* __restrict__ hsb,
    unsigned short* __restrict__ yf, unsigned short* __restrict__ yb)
{
  int c = blockIdx.x, b = blockIdx.y;
  int dir = blockIdx.z;
  const unsigned short* dt = dir? dtb : dtf;
  const unsigned short* u  = dir? ubb : ufb;
  const float* bmp= dir? bmb : bmf;
  const float* cmp= dir? cmb : cmf;
  const float* al = dir? alb : alf;
  const float* Dv = dir? Db  : Df;
  const float* hs = dir? hsb : hsf;
  unsigned short* yout = dir? yb : yf;
  int d = threadIdx.x;
  __shared__ float sB[CHL*NS];
  __shared__ float sC[CHL*NS];
  for (int i=threadIdx.x;i<CHL*NS;i+=256){
    sB[i] = bmp[((size_t)b*SQ + c*CHL)*NS + i];
    sC[i] = cmp[((size_t)b*SQ + c*CHL)*NS + i];
  }
  float A[NS], h[NS];
  size_t o = (((size_t)b*NCHK + c)*DM + d)*NS;
  #pragma unroll
  for (int n=0;n<NS;n++){ A[n] = -__expf(al[d*NS+n]); h[n] = hs[o+n]; }
  float Dd = Dv[d];
  __syncthreads();
  for (int t=0;t<CHL;t++){
    int gt = c*CHL + t;
    size_t idx = ((size_t)b*SQ + gt)*DM + d;
    float dtv = bf2f(dt[idx]);
    float uv  = bf2f(u[idx]);
    float du  = dtv*uv;
    float y = 0.f;
    #pragma unroll
    for (int n=0;n<NS;n++){
      h[n] = h[n]*__expf(dtv*A[n]) + du*sB[t*NS+n];
      y += h[n]*sC[t*NS+n];
    }
    y += uv*Dd;
    int torig = dir ? (SQ-1-gt) : gt;
    size_t oidx = ((size_t)b*SQ + torig)*DM + d;
    float zv = bf2f(zb[oidx]);
    yout[oidx] = f2bf(y * (zv * sigm_(zv)));
  }
}

// ---------- final: y-combine + out-LN (in LDS) + MFMA out_proj + post-LN + skip ----------
#define SOS 266
__global__ __launch_bounds__(256) void k_final2(
    const unsigned short* __restrict__ y16f, const unsigned short* __restrict__ y16b,
    const float* __restrict__ og, const float* __restrict__ ob,
    const unsigned short* __restrict__ Wb,
    const float* __restrict__ pg, const float* __restrict__ pb,
    const float* __restrict__ skip, float* __restrict__ out)
{
  __shared__ unsigned short yn[32][272];
  __shared__ float sOut[32*SOS];
  __shared__ float sm[32], sr[32];
  int tid = threadIdx.x;
  int wid = tid >> 6, lane = tid & 63;
  int row0 = blockIdx.x*32;
  // stage: combine halves + out-LN -> bf16 in LDS
  for (int j=0;j<8;j++){
    int rrow = wid*8 + j;
    size_t base = (size_t)(row0+rrow)*DM + lane*4;
    ushort4 hf = *(const ushort4*)(y16f + base);
    ushort4 hb = *(const ushort4*)(y16b + base);
    float4 v;
    v.x = 0.5f*(bf2f(hf.x)+bf2f(hb.x));
    v.y = 0.5f*(bf2f(hf.y)+bf2f(hb.y));
    v.z = 0.5f*(bf2f(hf.z)+bf2f(hb.z));
    v.w = 0.5f*(bf2f(hf.w)+bf2f(hb.w));
    float s = v.x+v.y+v.z+v.w;
    float ss = v.x*v.x+v.y*v.y+v.z*v.z+v.w*v.w;
    #pragma unroll
    for (int o=32;o>0;o>>=1){ s += __shfl_xor(s,o,64); ss += __shfl_xor(ss,o,64); }
    float m = s*(1.f/DM);
    float r = rsqrtf(ss*(1.f/DM)-m*m+1e-5f);
    float4 gv = *(const float4*)(og + lane*4);
    float4 bv = *(const float4*)(ob + lane*4);
    ushort4 o4;
    o4.x = f2bf((v.x-m)*r*gv.x+bv.x);
    o4.y = f2bf((v.y-m)*r*gv.y+bv.y);
    o4.z = f2bf((v.z-m)*r*gv.z+bv.z);
    o4.w = f2bf((v.w-m)*r*gv.w+bv.w);
    *(ushort4*)&yn[rrow][lane*4] = o4;
  }
  __syncthreads();
  int lr = lane & 15, lg = lane >> 4;
  int col0 = wid*64;
  f32x4 acc[2][4];
  #pragma unroll
  for (int m=0;m<2;m++)
    #pragma unroll
    for (int n=0;n<4;n++) acc[m][n] = (f32x4){0.f,0.f,0.f,0.f};
  #pragma unroll
  for (int k0=0;k0<DM;k0+=32){
    short8 a[2], b[4];
    #pragma unroll
    for (int m=0;m<2;m++)
      a[m] = *(const short8*)&yn[m*16 + lr][k0 + lg*8];
    #pragma unroll
    for (int n=0;n<4;n++)
      b[n] = *(const short8*)(Wb + (size_t)(col0 + n*16 + lr)*DM + k0 + lg*8);
    #pragma unroll
    for (int m=0;m<2;m++)
      #pragma unroll
      for (int n=0;n<4;n++)
        acc[m][n] = __builtin_amdgcn_mfma_f32_16x16x32_bf16(a[m], b[n], acc[m][n], 0,0,0);
  }
  #pragma unroll
  for (int m=0;m<2;m++)
    #pragma unroll
    for (int n=0;n<4;n++)
      #pragma unroll
      for (int r=0;r<4;r++)
        sOut[(m*16 + lg*4 + r)*SOS + col0 + n*16 + lr] = acc[m][n][r];
  __syncthreads();
  for (int j=0;j<8;j++){
    int rrow = wid*8 + j;
    const float* rp = &sOut[rrow*SOS + lane*4];
    float2 v0 = *(const float2*)(rp);
    float2 v1 = *(const float2*)(rp+2);
    float s = v0.x+v0.y+v1.x+v1.y;
    float ss = v0.x*v0.x+v0.y*v0.y+v1.x*v1.x+v1.y*v1.y;
    #pragma unroll
    for (int o=32;o>0;o>>=1){ s += __shfl_xor(s,o,64); ss += __shfl_xor(ss,o,64); }
    if (lane==0){ float m=s*(1.f/DM); sm[rrow]=m; sr[rrow]=rsqrtf(ss*(1.f/DM)-m*m+1e-5f); }
  }
  __syncthreads();
  float gv = pg[tid], bv = pb[tid];
  for (int rrow=0;rrow<32;rrow++){
    int tok = row0 + rrow;
    float v = (sOut[rrow*SOS + tid]-sm[rrow])*sr[rrow]*gv + bv + skip[(size_t)tok*DM + tid];
    out[(size_t)tok*DM + tid] = v;
  }
}

extern "C" void kernel_launch(void* const* d_in, const int* in_sizes, int n_in,
                              void* d_out, int out_size, void* d_ws, size_t ws_size,
                              hipStream_t stream)
{
  const float* input      = (const float*)d_in[0];
  const float* norm_g     = (const float*)d_in[1];
  const float* norm_b     = (const float*)d_in[2];
  const float* in_proj_w  = (const float*)d_in[3];
  const float* conv_w     = (const float*)d_in[4];
  const float* conv_b     = (const float*)d_in[5];
  const float* xproj_w    = (const float*)d_in[6];
  const float* dtproj_w   = (const float*)d_in[7];
  const float* dtproj_b   = (const float*)d_in[8];
  const float* A_log      = (const float*)d_in[9];
  const float* Dp         = (const float*)d_in[10];
  const float* conv_w_b   = (const float*)d_in[11];
  const float* conv_b_b   = (const float*)d_in[12];
  const float* xproj_w_b  = (const float*)d_in[13];
  const float* dtproj_w_b = (const float*)d_in[14];
  const float* dtproj_b_b = (const float*)d_in[15];
  const float* A_log_b    = (const float*)d_in[16];
  const float* Dp_b       = (const float*)d_in[17];
  const float* out_norm_g = (const float*)d_in[18];
  const float* out_norm_b = (const float*)d_in[19];
  const float* out_proj_w = (const float*)d_in[20];
  const float* post_norm_g= (const float*)d_in[21];
  const float* post_norm_b= (const float*)d_in[22];
  float* out = (float*)d_out;

  float* ws = (float*)d_ws;
  const size_t M2 = (size_t)NTOK*DM;           // 2,097,152 elements
  const size_t SCH = (size_t)BT*NCHK*DM*NS;    // 1,048,576 floats (4 MB)
  // slot0 (8MB): y16f / y16b bf16 (written by scan3, read by final2)
  unsigned short* y16f = (unsigned short*)ws;
  unsigned short* y16b = (unsigned short*)ws + M2;
  // slot1 (8MB): zb bf16 (4MB) + weight staging (4MB)
  unsigned short* zbuf = (unsigned short*)(ws + M2);
  unsigned short* auxw = (unsigned short*)(ws + M2 + M2/2);
  unsigned short* Wbin  = auxw;                    // 512x256 (256KB)
  unsigned short* Wcatb = auxw + 131072;           // 2x320x256 (320KB)
  unsigned short* Wbout = auxw + 131072 + 163840;  // 256x256 (128KB)
  // slot3 (8MB): dt bf16 fwd+bwd
  unsigned short* dt16f = (unsigned short*)(ws + 3*M2);
  unsigned short* dt16b = dt16f + M2;
  // slot4 (8MB): u bf16 fwd+bwd
  unsigned short* ufb = (unsigned short*)(ws + 4*M2);
  unsigned short* ubb = ufb + M2;
  // slot5: bm/cm (2MB) then ap/hs (16MB)
  float* p   = ws + 5*M2;
  float* bmf = p;              p += (size_t)NTOK*NS;
  float* cmf = p;              p += (size_t)NTOK*NS;
  float* bmb = p;              p += (size_t)NTOK*NS;
  float* cmb = p;              p += (size_t)NTOK*NS;
  float* apf = p;              p += SCH;
  float* hsf = p;              p += SCH;
  float* apb = p;              p += SCH;
  float* hsb = p;              p += SCH;
  // bf16 staging alias within apf (4MB): xl, live prep..inproj (before scan1)
  unsigned short* xlbf = (unsigned short*)apf;

  k_prep<<<NTOK/4 + 136 + 64, 256, 0, stream>>>(input, norm_g, norm_b, xlbf,
                                                in_proj_w, Wbin,
                                                xproj_w, xproj_w_b, dtproj_w, dtproj_w_b, Wcatb,
                                                out_proj_w, Wbout);
  k_inproj_conv<<<dim3(NTOK/128, 8, 1), 256, 0, stream>>>(xlbf, Wbin,
                                                          conv_w, conv_b, conv_w_b, conv_b_b,
                                                          ufb, ubb, zbuf);
  k_xproj_mfma<<<dim3(NTOK/128, 5, 2), 256, 0, stream>>>(ufb, ubb, Wcatb,
                                                         dtproj_b, dtproj_b_b,
                                                         dt16f, dt16b, bmf, cmf, bmb, cmb);
  k_scan1<<<dim3(NCHK, BT, 2), 256, 0, stream>>>(dt16f, dt16b, ufb, ubb, bmf, bmb,
                                                 A_log, A_log_b, apf, hsf, apb, hsb);
  k_scan2<<<256, 256, 0, stream>>>(apf, hsf, apb, hsb);
  k_scan3<<<dim3(NCHK, BT, 2), 256, 0, stream>>>(dt16f, dt16b, ufb, ubb, bmf, bmb, cmf, cmb,
                                                 A_log, A_log_b, Dp, Dp_b, zbuf, hsf, hsb,
                                                 y16f, y16b);
  k_final2<<<NTOK/32, 256, 0, stream>>>(y16f, y16b, out_norm_g, out_norm_b, Wbout,
                                        post_norm_g, post_norm_b, input, out);
}